// Round 10
// baseline (282.019 us; speedup 1.0000x reference)
//
#include <hip/hip_runtime.h>
#include <math.h>

#define B 4
#define L 2048
#define D 256
#define POSP 16
#define LTMP 16
#define T 64
#define C 32
#define F 72
#define PI_F 3.14159274101257324f
#define TWO_PI_D 6.283185307179586476925286766559

// -------- pos phasors (exact fp32 angle, double reduction) + Wt transpose -------
__global__ __launch_bounds__(256) void pos_kernel(const float* __restrict__ pos_freqs,
                                                  const float* __restrict__ lkp,
                                                  float* __restrict__ posc,
                                                  float* __restrict__ poss,
                                                  float* __restrict__ Wt) {
    int idx = blockIdx.x * 256 + threadIdx.x;
    if (idx < L * POSP) {
        int t = idx >> 4, p = idx & 15;
        float a = (float)t * pos_freqs[p];   // replicate numpy op order in fp32
        float th = (a * 2.0f) * PI_F;
        double r = fmod((double)th, TWO_PI_D);
        posc[idx] = (float)cos(r);
        poss[idx] = (float)sin(r);
    } else {
        int i2 = idx - L * POSP;             // transpose ltm_key_proj -> Wt[p][j]
        if (i2 < 16 * 768) {
            int p = i2 / 768, j = i2 - p * 768;
            Wt[i2] = lkp[j * 16 + p];
        }
    }
}

// ---------------- featurize: fused GEMM x @ [w_value | key_proj | query_proj] ---
// grid (4 col-groups of 64, 32 row-chunks of 64, B); 256 thr; 4x4 micro-tile;
// x staged TRANSPOSED with row stride 74 (conflict-free); double-buffered.
__global__ __launch_bounds__(256) void featurize_kernel(
    const float* __restrict__ x, const float* __restrict__ key_proj,
    const float* __restrict__ query_proj, const float* __restrict__ w_value,
    const float* __restrict__ b_value, const float* __restrict__ set_weights,
    float* __restrict__ V, float* __restrict__ fk, float* __restrict__ fq) {
    int cg = blockIdx.x;
    int rc = blockIdx.y;
    int b  = blockIdx.z;
    int row0 = rc * 64;
    int tid = threadIdx.x;
    __shared__ float xs[2][32][74];   // [buf][k][row] transposed x, stride 74
    __shared__ float ws[2][32][84];   // [buf][k][64 V-cols + 16 proj cols]
    __shared__ float zbuf[64][20];
    const bool has_proj = (cg < 2);
    const float* proj = (cg == 0) ? key_proj : query_proj;
    int rg = tid >> 4, cgi = tid & 15;
    int r0 = rg * 4, c0 = cgi * 4;
    int prow = tid >> 2, pc4 = tid & 3;
    float acc[4][4], accp[4];
#pragma unroll
    for (int i = 0; i < 4; i++) {
#pragma unroll
        for (int e = 0; e < 4; e++) acc[i][e] = 0.f;
        accp[i] = 0.f;
    }
    int rrA = tid >> 3, k4A = tid & 7;     // x stage mapping
    int jA = tid >> 4, c4A = tid & 15;     // w stage mapping
    float4 xr0, xr1, wr0, wr1, prr;

#define ISSUE_LOADS(kb_)                                                            \
    {                                                                               \
        xr0 = *(const float4*)(x + ((size_t)(b * L + row0 + rrA)) * D + (kb_) + k4A * 4);      \
        xr1 = *(const float4*)(x + ((size_t)(b * L + row0 + 32 + rrA)) * D + (kb_) + k4A * 4); \
        wr0 = *(const float4*)(w_value + (size_t)((kb_) + jA) * D + cg * 64 + c4A * 4);        \
        wr1 = *(const float4*)(w_value + (size_t)((kb_) + 16 + jA) * D + cg * 64 + c4A * 4);   \
        if (has_proj && tid < 128)                                                  \
            prr = *(const float4*)(proj + (size_t)((kb_) + (tid >> 2)) * 16 + (tid & 3) * 4);  \
    }
#define WRITE_LDS(bi)                                                               \
    {                                                                               \
        const float* xp0 = (const float*)&xr0;                                      \
        const float* xp1 = (const float*)&xr1;                                      \
        _Pragma("unroll")                                                           \
        for (int u = 0; u < 4; u++) {                                               \
            xs[bi][k4A * 4 + u][rrA] = xp0[u];                                      \
            xs[bi][k4A * 4 + u][32 + rrA] = xp1[u];                                 \
        }                                                                           \
        *(float4*)&ws[bi][jA][c4A * 4] = wr0;                                       \
        *(float4*)&ws[bi][16 + jA][c4A * 4] = wr1;                                  \
        if (has_proj && tid < 128)                                                  \
            *(float4*)&ws[bi][tid >> 2][64 + (tid & 3) * 4] = prr;                  \
    }

    ISSUE_LOADS(0);
    WRITE_LDS(0);
    __syncthreads();
    for (int kc = 0; kc < 8; kc++) {
        if (kc < 7) ISSUE_LOADS((kc + 1) * 32);
        int bi = kc & 1;
#pragma unroll 8
        for (int j = 0; j < 32; j++) {
            float2 xlo = *(float2*)&xs[bi][j][r0];
            float2 xhi = *(float2*)&xs[bi][j][r0 + 2];
            float4 wv = *(float4*)&ws[bi][j][c0];
            acc[0][0] += xlo.x * wv.x; acc[0][1] += xlo.x * wv.y; acc[0][2] += xlo.x * wv.z; acc[0][3] += xlo.x * wv.w;
            acc[1][0] += xlo.y * wv.x; acc[1][1] += xlo.y * wv.y; acc[1][2] += xlo.y * wv.z; acc[1][3] += xlo.y * wv.w;
            acc[2][0] += xhi.x * wv.x; acc[2][1] += xhi.x * wv.y; acc[2][2] += xhi.x * wv.z; acc[2][3] += xhi.x * wv.w;
            acc[3][0] += xhi.y * wv.x; acc[3][1] += xhi.y * wv.y; acc[3][2] += xhi.y * wv.z; acc[3][3] += xhi.y * wv.w;
            if (has_proj) {
                float xp = xs[bi][j][prow];
                float4 wp = *(float4*)&ws[bi][j][64 + pc4 * 4];
                accp[0] += xp * wp.x; accp[1] += xp * wp.y;
                accp[2] += xp * wp.z; accp[3] += xp * wp.w;
            }
        }
        if (kc < 7) WRITE_LDS((kc + 1) & 1);
        __syncthreads();
    }
#undef ISSUE_LOADS
#undef WRITE_LDS

    // V epilogue
    {
        int d0 = cg * 64 + c0;
        float4 bv = *(const float4*)(b_value + d0);
#pragma unroll
        for (int i = 0; i < 4; i++) {
            size_t o = ((size_t)(b * L + row0 + r0 + i)) * D + d0;
            *(float4*)(V + o) = make_float4(acc[i][0] + bv.x, acc[i][1] + bv.y,
                                            acc[i][2] + bv.z, acc[i][3] + bv.w);
        }
    }
    if (!has_proj) return;
#pragma unroll
    for (int e = 0; e < 4; e++) zbuf[prow][pc4 * 4 + e] = tanhf(accp[e]) * PI_F;
    __syncthreads();
    // phasor epilogue: 64 rows x 4 threads; thread handles 4 cols + joint plane q
    {
        int tt = tid >> 2, q = tid & 3;
        size_t bt = (size_t)(b * L + row0 + tt);
        if (cg == 0) {
            float* fp = fk + bt * 40;
#pragma unroll
            for (int e = 0; e < 4; e++) {
                int col = q * 4 + e;
                float si, co; sincosf(zbuf[tt][col], &si, &co);
                fp[2 * col] = co; fp[2 * col + 1] = si;
            }
            float zs = zbuf[tt][q] + zbuf[tt][4 + q] + zbuf[tt][8 + q] + zbuf[tt][12 + q];
            float si, co; sincosf(zs, &si, &co);
            fp[32 + 2 * q] = co; fp[33 + 2 * q] = si;
        } else {
            float sw0 = set_weights[0], sw1 = set_weights[1], sw2 = set_weights[2], sw3 = set_weights[3];
            float mx = fmaxf(fmaxf(sw0, sw1), fmaxf(sw2, sw3));
            float e0 = expf(sw0 - mx), e1 = expf(sw1 - mx), e2 = expf(sw2 - mx), e3 = expf(sw3 - mx);
            float esum = e0 + e1 + e2 + e3;
            float wsoft[4] = {e0 / esum, e1 / esum, e2 / esum, e3 / esum};
            float* fp = fq + bt * 40;
#pragma unroll
            for (int e = 0; e < 4; e++) {
                int col = q * 4 + e;
                float si, co; sincosf(zbuf[tt][col], &si, &co);
                float sc = 0.1f * wsoft[col >> 2];   // 0.5 * w_s / (NSETS+1)
                fp[2 * col] = sc * co; fp[2 * col + 1] = sc * si;
            }
            float zs = zbuf[tt][q] + zbuf[tt][4 + q] + zbuf[tt][8 + q] + zbuf[tt][12 + q];
            float si, co; sincosf(zs, &si, &co);
            fp[32 + 2 * q] = 0.1f * co; fp[33 + 2 * q] = 0.1f * si;
        }
    }
}

// -------- fused gate: block-wide exclusive scan of jk + gate + scale fk ---------
// grid (B); 1024 threads; thread owns rows 2t, 2t+1.
__global__ __launch_bounds__(1024) void gate_kernel(
    float* __restrict__ fk,
    const float* __restrict__ surprise_scale, const float* __restrict__ surprise_bias,
    const float* __restrict__ resonance_scale, const float* __restrict__ resonance_threshold) {
    int b = blockIdx.x;
    int tid = threadIdx.x;
    __shared__ float scan[1024][8];
    float j0[8], j1[8], tot[8];
    float* fp0 = fk + ((size_t)(b * L + tid * 2)) * 40;
    float* fp1 = fk + ((size_t)(b * L + tid * 2 + 1)) * 40;
#pragma unroll
    for (int q = 0; q < 8; q++) {
        j0[q] = fp0[32 + q];
        j1[q] = fp1[32 + q];
        tot[q] = j0[q] + j1[q];
        scan[tid][q] = tot[q];
    }
    __syncthreads();
    for (int off = 1; off < 1024; off <<= 1) {
        float tmp[8];
        if (tid >= off) {
#pragma unroll
            for (int q = 0; q < 8; q++) tmp[q] = scan[tid - off][q];
        }
        __syncthreads();
        if (tid >= off) {
#pragma unroll
            for (int q = 0; q < 8; q++) scan[tid][q] += tmp[q];
        }
        __syncthreads();
    }
    float run[8];
#pragma unroll
    for (int q = 0; q < 8; q++) run[q] = scan[tid][q] - tot[q];   // exclusive
    float ss = surprise_scale[0], sb = surprise_bias[0];
    float scv = fminf(fmaxf(resonance_scale[0], 1.f), 20.f);
    float thv = fminf(fmaxf(resonance_threshold[0], 0.1f), 0.9f);
#pragma unroll
    for (int k = 0; k < 2; k++) {
        int t = tid * 2 + k;
        float* fp = k ? fp1 : fp0;
        float rmag = 0.25f * (sqrtf(run[0] * run[0] + run[1] * run[1]) +
                              sqrtf(run[2] * run[2] + run[3] * run[3]) +
                              sqrtf(run[4] * run[4] + run[5] * run[5]) +
                              sqrtf(run[6] * run[6] + run[7] * run[7]));
        float nres = rmag / sqrtf(fmaxf((float)t, 1.0f));
        float surprise = 0.5f * (1.0f - tanhf(scv * (nres - thv)));
        float gate = 1.0f / (1.0f + expf(-(ss * (surprise - 0.5f) + sb)));
#pragma unroll
        for (int q = 0; q < 8; q++) run[q] += (k ? j1[q] : j0[q]);
#pragma unroll
        for (int q = 0; q < 40; q++) fp[q] *= gate;
    }
}

// ---------------- 16-row sub-chunk sums of x, x^2 (LTM stats) -------------------
__global__ __launch_bounds__(256) void stats16_kernel(const float* __restrict__ x,
                                                      float* __restrict__ Sx16,
                                                      float* __restrict__ Sxx16) {
    int s = blockIdx.x, b = blockIdx.y;
    int d = threadIdx.x;
    float sx = 0.f, sxx = 0.f;
#pragma unroll
    for (int k = 0; k < 16; k++) {
        float v = x[((size_t)(b * L + s * 16 + k)) * D + d];
        sx += v; sxx += v * v;
    }
    Sx16[((size_t)(b * 128 + s)) * D + d] = sx;
    Sxx16[((size_t)(b * 128 + s)) * D + d] = sxx;
}

// ---------------- LTM phasor angles, 16 rows per block --------------------------
// Dot phase mapping: tl = tid&15, p = tid>>4 -> Wt float4 reads wave-broadcast.
__global__ __launch_bounds__(256) void ltm_z_kernel(
    const float* __restrict__ x, const float* __restrict__ Sx16,
    const float* __restrict__ Sxx16, const float* __restrict__ Wt,
    float* __restrict__ czsz) {
    int s = blockIdx.x, b = blockIdx.y;
    int tid = threadIdx.x;
    __shared__ float xs[16][260], rms[16][260], rss[16][260];
    float a0 = 0.f, a1 = 0.f, a2 = 0.f, a3 = 0.f;
    float c0 = 0.f, c1 = 0.f, c2 = 0.f, c3 = 0.f;
    int sp = 0;
    for (; sp + 4 <= s; sp += 4) {
        a0 += Sx16[((size_t)(b * 128 + sp)) * D + tid];
        a1 += Sx16[((size_t)(b * 128 + sp + 1)) * D + tid];
        a2 += Sx16[((size_t)(b * 128 + sp + 2)) * D + tid];
        a3 += Sx16[((size_t)(b * 128 + sp + 3)) * D + tid];
        c0 += Sxx16[((size_t)(b * 128 + sp)) * D + tid];
        c1 += Sxx16[((size_t)(b * 128 + sp + 1)) * D + tid];
        c2 += Sxx16[((size_t)(b * 128 + sp + 2)) * D + tid];
        c3 += Sxx16[((size_t)(b * 128 + sp + 3)) * D + tid];
    }
    for (; sp < s; sp++) {
        a0 += Sx16[((size_t)(b * 128 + sp)) * D + tid];
        c0 += Sxx16[((size_t)(b * 128 + sp)) * D + tid];
    }
    float runx = (a0 + a1) + (a2 + a3), runxx = (c0 + c1) + (c2 + c3);
    for (int k = 0; k < 16; k++) {
        int tg = s * 16 + k;
        float xv = x[((size_t)(b * L + tg)) * D + tid];
        runx += xv; runxx += xv * xv;
        float n = (float)(tg + 1);
        float rm = runx / n;
        float rv = runxx / n - rm * rm;
        xs[k][tid] = xv; rms[k][tid] = rm;
        rss[k][tid] = sqrtf(fmaxf(rv, 1e-8f));
    }
    __syncthreads();
    int tl = tid & 15, p = tid >> 4;
    const float* W0 = Wt + p * 768;
    float u0 = 0.f, u1 = 0.f, u2 = 0.f;
#pragma unroll 4
    for (int j4 = 0; j4 < 64; j4++) {
        float4 xv = *(float4*)&xs[tl][j4 * 4];
        float4 wx = *(const float4*)(W0 + j4 * 4);
        float4 rv = *(float4*)&rms[tl][j4 * 4];
        float4 wr = *(const float4*)(W0 + 256 + j4 * 4);
        float4 sv = *(float4*)&rss[tl][j4 * 4];
        float4 wz = *(const float4*)(W0 + 512 + j4 * 4);
        u0 += xv.x * wx.x + xv.y * wx.y + xv.z * wx.z + xv.w * wx.w;
        u1 += rv.x * wr.x + rv.y * wr.y + rv.z * wr.z + rv.w * wr.w;
        u2 += sv.x * wz.x + sv.y * wz.y + sv.z * wz.z + sv.w * wz.w;
    }
    float z = tanhf(u0 + u1 + u2) * PI_F;
    float si, co; sincosf(z, &si, &co);
    int tg = s * 16 + tl;
    czsz[((size_t)(b * L + tg)) * 32 + p] = co;
    czsz[((size_t)(b * L + tg)) * 32 + 16 + p] = si;
}

// ------------- half-chunk outer-product sums Sh[b,c,h,f,d] (32-t halves) --------
__global__ __launch_bounds__(256) void outer_sums_kernel(
    const float* __restrict__ V, const float* __restrict__ fk,
    const float* __restrict__ posc, const float* __restrict__ poss,
    float* __restrict__ Sh) {
    int g = blockIdx.x >> 1, h = blockIdx.x & 1;
    int c = blockIdx.y;
    int b = blockIdx.z;
    int tid = threadIdx.x;
    __shared__ float Fk[32][40];
    int F0 = g * 36;
    {
        int t = tid >> 3, q = tid & 7;
        int tg = c * T + h * 32 + t;
#pragma unroll
        for (int e = 0; e < 5; e++) {
            int fl = q * 5 + e;
            float v = 0.f;
            if (fl < 36) {
                int Fi = F0 + fl;
                if (Fi < 40) v = fk[((size_t)(b * L + tg)) * 40 + Fi];
                else {
                    int pf = Fi - 40;
                    v = (pf & 1) ? poss[tg * POSP + (pf >> 1)] : posc[tg * POSP + (pf >> 1)];
                }
            }
            Fk[t][fl] = v;
        }
    }
    __syncthreads();
    float acc[36];
#pragma unroll
    for (int f = 0; f < 36; f++) acc[f] = 0.f;
    for (int t = 0; t < 32; t++) {
        float v = V[((size_t)(b * L + c * T + h * 32 + t)) * D + tid];
#pragma unroll
        for (int f4 = 0; f4 < 9; f4++) {
            float4 fkv = *(float4*)&Fk[t][f4 * 4];
            acc[f4 * 4 + 0] += fkv.x * v;
            acc[f4 * 4 + 1] += fkv.y * v;
            acc[f4 * 4 + 2] += fkv.z * v;
            acc[f4 * 4 + 3] += fkv.w * v;
        }
    }
    for (int f = 0; f < 36; f++)
        Sh[((((size_t)(b * C + c)) * 2 + h) * F + F0 + f) * D + tid] = acc[f];
}

// ------- exclusive prefix over chunks, combining half-chunk sums ---------------
__global__ __launch_bounds__(256) void prefix_kernel(const float* __restrict__ Sh,
                                                     float* __restrict__ S) {
    int bf = blockIdx.x;
    int b = bf / F, f = bf % F;
    int d = threadIdx.x;
    float v0[C], v1[C];
#pragma unroll
    for (int c = 0; c < C; c++) {
        v0[c] = Sh[((((size_t)(b * C + c)) * 2 + 0) * F + f) * D + d];
        v1[c] = Sh[((((size_t)(b * C + c)) * 2 + 1) * F + f) * D + d];
    }
    float run = 0.f;
#pragma unroll
    for (int c = 0; c < C; c++) {
        S[(((size_t)(b * C + c)) * F + f) * D + d] = run;
        run += v0[c] + v1[c];
    }
}

// ------ intra fused w/ hprep: hn = LN((Fq·M + A·V + lcoef*pers)/nrm)*g + b ------
// grid (4 tg, 32 c, B); 256 threads; thread owns column d = tid, 16 rows.
// A computed once per tg; Fk LDS region aliased as hb for the LN phase.
__global__ __launch_bounds__(256) void intra_kernel(
    const float* __restrict__ V, float* __restrict__ hn,
    const float* __restrict__ fk, const float* __restrict__ fq,
    const float* __restrict__ posc, const float* __restrict__ poss,
    const float* __restrict__ Mexc, const float* __restrict__ pos_weight,
    const float* __restrict__ czsz, const float* __restrict__ ltm_mem,
    const float* __restrict__ ltm_count, const float* __restrict__ ltm_weight,
    const float* __restrict__ ln_gamma, const float* __restrict__ ln_beta) {
    int tg = blockIdx.x, c = blockIdx.y, b = blockIdx.z;
    int tid = threadIdx.x;
    int t0 = tg * 16;
    __shared__ float smem[8384];
    float (*Fk)[76] = (float(*)[76])smem;              // 64*76 = 4864
    float (*Fq)[76] = (float(*)[76])(smem + 4864);     // 16*76 = 1216 -> 6080
    float (*As)[68] = (float(*)[68])(smem + 6080);     // 16*68 = 1088 -> 7168
    float (*cs)[33]  = (float(*)[33])(smem + 7168);    // 16*33 = 528 -> 7696
    float (*part1)[17] = (float(*)[17])(smem + 7696);  // 272 -> 7968
    float (*part2)[17] = (float(*)[17])(smem + 7968);  // 272 -> 8240
    float* mu   = smem + 8240;                          // 16
    float* rsig = smem + 8256;                          // 16
    float (*hb)[260] = (float(*)[260])smem;            // aliases Fk (4160 <= 4864)
    float posq = 0.5f / (1.0f + expf(-pos_weight[0]));
    // stage Fk (full chunk) and Fq (16 rows)
#pragma unroll
    for (int e = 0; e < 18; e++) {
        int idx = e * 256 + tid;
        int r = idx / 72, f = idx - r * 72;
        int tgl = c * T + r;
        float v;
        if (f < 40) v = fk[((size_t)(b * L + tgl)) * 40 + f];
        else { int pf = f - 40; v = (pf & 1) ? poss[tgl * POSP + (pf >> 1)] : posc[tgl * POSP + (pf >> 1)]; }
        Fk[r][f] = v;
    }
#pragma unroll
    for (int e = 0; e < 5; e++) {
        int idx = e * 256 + tid;
        if (idx < 1152) {
            int r = idx / 72, f = idx - r * 72;
            int tgl = c * T + t0 + r;
            float v;
            if (f < 40) v = fq[((size_t)(b * L + tgl)) * 40 + f];
            else { int pf = f - 40; v = posq * ((pf & 1) ? poss[tgl * POSP + (pf >> 1)] : posc[tgl * POSP + (pf >> 1)]); }
            Fq[r][f] = v;
        }
    }
    // stage czsz for these 16 rows
    {
        int idx2 = tid;             // 512 = 16 rows x 32; two passes
#pragma unroll
        for (int e = 0; e < 2; e++) {
            int idx = e * 256 + idx2;
            int t = idx >> 5, q = idx & 31;
            cs[t][q] = czsz[((size_t)(b * L + c * T + t0 + t)) * 32 + q];
        }
    }
    __syncthreads();
    // A[r][k] (16 x 64, 4 k's per thread), causal
    {
        int r = tid >> 4, k0 = (tid & 15) * 4;
        int tglob = t0 + r;
#pragma unroll
        for (int j = 0; j < 4; j++) {
            int k = k0 + j;
            float a = 0.f;
            if (k <= tglob) {
#pragma unroll
                for (int f4 = 0; f4 < 18; f4++) {
                    float4 q = *(float4*)&Fq[r][f4 * 4];
                    float4 kk = *(float4*)&Fk[k][f4 * 4];
                    a += q.x * kk.x + q.y * kk.y + q.z * kk.z + q.w * kk.w;
                }
            }
            As[r][k] = a;
        }
    }
    __syncthreads();   // last Fk read done; Fk region may be overwritten as hb
    // main: thread owns column d = tid, 16 rows
    int d = tid;
    float acc[16];
#pragma unroll
    for (int i = 0; i < 16; i++) acc[i] = 0.f;
    const float* Mp = Mexc + (((size_t)(b * C + c)) * F) * D + d;
#pragma unroll 8
    for (int f = 0; f < F; f++) {
        float m = Mp[(size_t)f * D];
#pragma unroll
        for (int i = 0; i < 16; i++) acc[i] += Fq[i][f] * m;
    }
    const float* Vp = V + ((size_t)(b * L + c * T)) * D + d;
    int kmax = t0 + 16;
#pragma unroll 8
    for (int k = 0; k < kmax; k++) {
        float v = Vp[(size_t)k * D];
#pragma unroll
        for (int i = 0; i < 16; i++) acc[i] += As[i][k] * v;
    }
    // + LTM pers, /nrm -> hb
    float lsig = 1.f / (1.f + expf(-ltm_weight[0]));
    float pnorm = sqrtf(fmaxf(ltm_count[0], 1.f) * (float)LTMP);
    float lcoef = lsig / pnorm;
    float Mre[16], Mim[16];
#pragma unroll
    for (int p = 0; p < 16; p++) {
        Mre[p] = ltm_mem[(p * D + d) * 2];
        Mim[p] = ltm_mem[(p * D + d) * 2 + 1];
    }
#pragma unroll
    for (int i = 0; i < 16; i++) {
        float pers = 0.f;
#pragma unroll
        for (int p = 0; p < 16; p++) pers += Mre[p] * cs[i][p] + Mim[p] * cs[i][16 + p];
        int tgl = c * T + t0 + i;
        acc[i] = (acc[i] + lcoef * pers) / (2.0f * sqrtf((float)(tgl + 1)));
    }
    __syncthreads();   // everyone past Fk reads (redundant but safe before hb writes)
#pragma unroll
    for (int i = 0; i < 16; i++) hb[i][d] = acc[i];
    __syncthreads();
    // LN stats: row = tid&15, e = tid>>4; cols e+16k (2-way banks, free)
    {
        int row = tid & 15, e = tid >> 4;
        float s1 = 0.f, s2 = 0.f;
#pragma unroll
        for (int k = 0; k < 16; k++) {
            float v = hb[row][e + 16 * k];
            s1 += v; s2 += v * v;
        }
        part1[row][e] = s1; part2[row][e] = s2;
    }
    __syncthreads();
    if (tid < 16) {
        float s1 = 0.f, s2 = 0.f;
#pragma unroll
        for (int e = 0; e < 16; e++) { s1 += part1[tid][e]; s2 += part2[tid][e]; }
        float m = s1 / 256.f;
        mu[tid] = m;
        rsig[tid] = rsqrtf(fmaxf(s2 / 256.f - m * m, 0.f) + 1e-5f);
    }
    __syncthreads();
    float gam = ln_gamma[d], bet = ln_beta[d];
#pragma unroll
    for (int i = 0; i < 16; i++)
        hn[((size_t)(b * L + c * T + t0 + i)) * D + d] =
            (acc[i] - mu[i]) * rsig[i] * gam + bet;
}

// ---------------- gemm_out: out = x + hn @ w_out + b_out ------------------------
__global__ __launch_bounds__(256) void gemm_out_kernel(
    const float* __restrict__ hn, const float* __restrict__ w_out,
    const float* __restrict__ b_out, const float* __restrict__ x,
    float* __restrict__ out) {
    int cg = blockIdx.x;
    int rc = blockIdx.y;
    int b  = blockIdx.z;
    int row0 = rc * 64;
    int tid = threadIdx.x;
    __shared__ float hs[2][32][74];
    __shared__ float wo[2][32][68];
    int rg = tid >> 4, cgi = tid & 15;
    int r0 = rg * 4, c0 = cgi * 4;
    float acc[4][4];
#pragma unroll
    for (int i = 0; i < 4; i++)
#pragma unroll
        for (int e = 0; e < 4; e++) acc[i][e] = 0.f;
    int rrA = tid >> 3, k4A = tid & 7;
    int jA = tid >> 4, c4A = tid & 15;
    float4 hr0, hr1, wr0, wr1;

#define ISSUE_LOADS(kb_)                                                            \
    {                                                                               \
        hr0 = *(const float4*)(hn + ((size_t)(b * L + row0 + rrA)) * D + (kb_) + k4A * 4);      \
        hr1 = *(const float4*)(hn + ((size_t)(b * L + row0 + 32 + rrA)) * D + (kb_) + k4A * 4); \
        wr0 = *(const float4*)(w_out + (size_t)((kb_) + jA) * D + cg * 64 + c4A * 4);           \
        wr1 = *(const float4*)(w_out + (size_t)((kb_) + 16 + jA) * D + cg * 64 + c4A * 4);      \
    }
#define WRITE_LDS(bi)                                                               \
    {                                                                               \
        const float* hp0 = (const float*)&hr0;                                      \
        const float* hp1 = (const float*)&hr1;                                      \
        _Pragma("unroll")                                                           \
        for (int u = 0; u < 4; u++) {                                               \
            hs[bi][k4A * 4 + u][rrA] = hp0[u];                                      \
            hs[bi][k4A * 4 + u][32 + rrA] = hp1[u];                                 \
        }                                                                           \
        *(float4*)&wo[bi][jA][c4A * 4] = wr0;                                       \
        *(float4*)&wo[bi][16 + jA][c4A * 4] = wr1;                                  \
    }

    ISSUE_LOADS(0);
    WRITE_LDS(0);
    __syncthreads();
    for (int kc = 0; kc < 8; kc++) {
        if (kc < 7) ISSUE_LOADS((kc + 1) * 32);
        int bi = kc & 1;
#pragma unroll 8
        for (int j = 0; j < 32; j++) {
            float2 xlo = *(float2*)&hs[bi][j][r0];
            float2 xhi = *(float2*)&hs[bi][j][r0 + 2];
            float4 wv = *(float4*)&wo[bi][j][c0];
            acc[0][0] += xlo.x * wv.x; acc[0][1] += xlo.x * wv.y; acc[0][2] += xlo.x * wv.z; acc[0][3] += xlo.x * wv.w;
            acc[1][0] += xlo.y * wv.x; acc[1][1] += xlo.y * wv.y; acc[1][2] += xlo.y * wv.z; acc[1][3] += xlo.y * wv.w;
            acc[2][0] += xhi.x * wv.x; acc[2][1] += xhi.x * wv.y; acc[2][2] += xhi.x * wv.z; acc[2][3] += xhi.x * wv.w;
            acc[3][0] += xhi.y * wv.x; acc[3][1] += xhi.y * wv.y; acc[3][2] += xhi.y * wv.z; acc[3][3] += xhi.y * wv.w;
        }
        if (kc < 7) WRITE_LDS((kc + 1) & 1);
        __syncthreads();
    }
#undef ISSUE_LOADS
#undef WRITE_LDS
    {
        int d0 = cg * 64 + c0;
        float4 bo = *(const float4*)(b_out + d0);
#pragma unroll
        for (int i = 0; i < 4; i++) {
            size_t o = ((size_t)(b * L + row0 + r0 + i)) * D + d0;
            float4 xa = *(const float4*)(x + o);
            *(float4*)(out + o) = make_float4(xa.x + acc[i][0] + bo.x, xa.y + acc[i][1] + bo.y,
                                              xa.z + acc[i][2] + bo.z, xa.w + acc[i][3] + bo.w);
        }
    }
}

extern "C" void kernel_launch(void* const* d_in, const int* in_sizes, int n_in,
                              void* d_out, int out_size, void* d_ws, size_t ws_size,
                              hipStream_t stream) {
    (void)in_sizes; (void)n_in; (void)out_size; (void)ws_size;
    const float* x            = (const float*)d_in[0];
    const float* key_proj     = (const float*)d_in[1];
    const float* query_proj   = (const float*)d_in[2];
    const float* ltm_key_proj = (const float*)d_in[3];
    const float* pos_freqs    = (const float*)d_in[4];
    const float* w_value      = (const float*)d_in[5];
    const float* b_value      = (const float*)d_in[6];
    const float* ln_gamma     = (const float*)d_in[9];
    const float* ln_beta      = (const float*)d_in[10];
    const float* w_out        = (const float*)d_in[11];
    const float* b_out        = (const float*)d_in[12];
    const float* set_weights  = (const float*)d_in[13];
    const float* pos_weight   = (const float*)d_in[14];
    const float* surprise_scale      = (const float*)d_in[15];
    const float* surprise_bias       = (const float*)d_in[16];
    const float* resonance_scale     = (const float*)d_in[17];
    const float* resonance_threshold = (const float*)d_in[18];
    const float* ltm_weight   = (const float*)d_in[19];
    const float* ltm_mem      = (const float*)d_in[20];
    const float* ltm_count    = (const float*)d_in[21];
    float* out = (float*)d_out;

    float* ws = (float*)d_ws;
    size_t off = 0;
    float* V     = ws + off; off += (size_t)B * L * D;
    float* hn    = ws + off; off += (size_t)B * L * D;
    float* fk    = ws + off; off += (size_t)B * L * 40;
    float* fq    = ws + off; off += (size_t)B * L * 40;
    float* posc  = ws + off; off += (size_t)L * POSP;
    float* poss  = ws + off; off += (size_t)L * POSP;
    float* Sx16  = ws + off; off += (size_t)B * 128 * D;
    float* Sxx16 = ws + off; off += (size_t)B * 128 * D;
    float* czsz  = ws + off; off += (size_t)B * L * 32;
    float* Sh    = ws + off; off += (size_t)B * C * 2 * F * D;   // half-chunk sums
    float* S     = ws + off; off += (size_t)B * C * F * D;       // exclusive prefix
    float* Wt    = ws + off; off += (size_t)16 * 768;

    pos_kernel<<<dim3(176), 256, 0, stream>>>(pos_freqs, ltm_key_proj, posc, poss, Wt);
    featurize_kernel<<<dim3(4, 32, B), 256, 0, stream>>>(x, key_proj, query_proj, w_value,
                                                         b_value, set_weights, V, fk, fq);
    gate_kernel<<<dim3(B), 1024, 0, stream>>>(fk, surprise_scale, surprise_bias,
                                              resonance_scale, resonance_threshold);
    stats16_kernel<<<dim3(128, B), 256, 0, stream>>>(x, Sx16, Sxx16);
    ltm_z_kernel<<<dim3(128, B), 256, 0, stream>>>(x, Sx16, Sxx16, Wt, czsz);
    outer_sums_kernel<<<dim3(4, C, B), 256, 0, stream>>>(V, fk, posc, poss, Sh);
    prefix_kernel<<<dim3(B * F), 256, 0, stream>>>(Sh, S);
    intra_kernel<<<dim3(4, C, B), 256, 0, stream>>>(V, hn, fk, fq, posc, poss, S, pos_weight,
                                                    czsz, ltm_mem, ltm_count, ltm_weight,
                                                    ln_gamma, ln_beta);
    gemm_out_kernel<<<dim3(4, 32, B), 256, 0, stream>>>(hn, w_out, b_out, x, out);
}

// Round 11
// 264.056 us; speedup vs baseline: 1.0680x; 1.0680x over previous
//
#include <hip/hip_runtime.h>
#include <math.h>

#define B 4
#define L 2048
#define D 256
#define POSP 16
#define LTMP 16
#define T 64
#define C 32
#define F 72
#define PI_F 3.14159274101257324f
#define TWO_PI_D 6.283185307179586476925286766559

// -- pos phasors (exact fp32 angle, double reduction), INTERLEAVED + Wt transpose --
// posci[t][2p] = cos, posci[t][2p+1] = sin  (== feature order used by consumers)
__global__ __launch_bounds__(256) void pos_kernel(const float* __restrict__ pos_freqs,
                                                  const float* __restrict__ lkp,
                                                  float* __restrict__ posci,
                                                  float* __restrict__ Wt) {
    int idx = blockIdx.x * 256 + threadIdx.x;
    if (idx < L * POSP) {
        int t = idx >> 4, p = idx & 15;
        float a = (float)t * pos_freqs[p];   // replicate numpy op order in fp32
        float th = (a * 2.0f) * PI_F;
        double r = fmod((double)th, TWO_PI_D);
        posci[t * 32 + 2 * p] = (float)cos(r);
        posci[t * 32 + 2 * p + 1] = (float)sin(r);
    } else {
        int i2 = idx - L * POSP;             // transpose ltm_key_proj -> Wt[p][j]
        if (i2 < 16 * 768) {
            int p = i2 / 768, j = i2 - p * 768;
            Wt[i2] = lkp[j * 16 + p];
        }
    }
}

// ---------------- featurize: fused GEMM x @ [w_value | key_proj | query_proj] ---
// grid (4 col-groups of 64, 32 row-chunks of 64, B); 256 thr; 4x4 micro-tile;
// x staged TRANSPOSED with row stride 74 (conflict-free); double-buffered.
__global__ __launch_bounds__(256) void featurize_kernel(
    const float* __restrict__ x, const float* __restrict__ key_proj,
    const float* __restrict__ query_proj, const float* __restrict__ w_value,
    const float* __restrict__ b_value, const float* __restrict__ set_weights,
    float* __restrict__ V, float* __restrict__ fk, float* __restrict__ fq) {
    int cg = blockIdx.x;
    int rc = blockIdx.y;
    int b  = blockIdx.z;
    int row0 = rc * 64;
    int tid = threadIdx.x;
    __shared__ float xs[2][32][74];   // [buf][k][row] transposed x, stride 74
    __shared__ float ws[2][32][84];   // [buf][k][64 V-cols + 16 proj cols]
    __shared__ float zbuf[64][20];
    const bool has_proj = (cg < 2);
    const float* proj = (cg == 0) ? key_proj : query_proj;
    int rg = tid >> 4, cgi = tid & 15;
    int r0 = rg * 4, c0 = cgi * 4;
    int prow = tid >> 2, pc4 = tid & 3;
    float acc[4][4], accp[4];
#pragma unroll
    for (int i = 0; i < 4; i++) {
#pragma unroll
        for (int e = 0; e < 4; e++) acc[i][e] = 0.f;
        accp[i] = 0.f;
    }
    int rrA = tid >> 3, k4A = tid & 7;     // x stage mapping
    int jA = tid >> 4, c4A = tid & 15;     // w stage mapping
    float4 xr0, xr1, wr0, wr1, prr;

#define ISSUE_LOADS(kb_)                                                            \
    {                                                                               \
        xr0 = *(const float4*)(x + ((size_t)(b * L + row0 + rrA)) * D + (kb_) + k4A * 4);      \
        xr1 = *(const float4*)(x + ((size_t)(b * L + row0 + 32 + rrA)) * D + (kb_) + k4A * 4); \
        wr0 = *(const float4*)(w_value + (size_t)((kb_) + jA) * D + cg * 64 + c4A * 4);        \
        wr1 = *(const float4*)(w_value + (size_t)((kb_) + 16 + jA) * D + cg * 64 + c4A * 4);   \
        if (has_proj && tid < 128)                                                  \
            prr = *(const float4*)(proj + (size_t)((kb_) + (tid >> 2)) * 16 + (tid & 3) * 4);  \
    }
#define WRITE_LDS(bi)                                                               \
    {                                                                               \
        const float* xp0 = (const float*)&xr0;                                      \
        const float* xp1 = (const float*)&xr1;                                      \
        _Pragma("unroll")                                                           \
        for (int u = 0; u < 4; u++) {                                               \
            xs[bi][k4A * 4 + u][rrA] = xp0[u];                                      \
            xs[bi][k4A * 4 + u][32 + rrA] = xp1[u];                                 \
        }                                                                           \
        *(float4*)&ws[bi][jA][c4A * 4] = wr0;                                       \
        *(float4*)&ws[bi][16 + jA][c4A * 4] = wr1;                                  \
        if (has_proj && tid < 128)                                                  \
            *(float4*)&ws[bi][tid >> 2][64 + (tid & 3) * 4] = prr;                  \
    }

    ISSUE_LOADS(0);
    WRITE_LDS(0);
    __syncthreads();
    for (int kc = 0; kc < 8; kc++) {
        if (kc < 7) ISSUE_LOADS((kc + 1) * 32);
        int bi = kc & 1;
#pragma unroll 8
        for (int j = 0; j < 32; j++) {
            float2 xlo = *(float2*)&xs[bi][j][r0];
            float2 xhi = *(float2*)&xs[bi][j][r0 + 2];
            float4 wv = *(float4*)&ws[bi][j][c0];
            acc[0][0] += xlo.x * wv.x; acc[0][1] += xlo.x * wv.y; acc[0][2] += xlo.x * wv.z; acc[0][3] += xlo.x * wv.w;
            acc[1][0] += xlo.y * wv.x; acc[1][1] += xlo.y * wv.y; acc[1][2] += xlo.y * wv.z; acc[1][3] += xlo.y * wv.w;
            acc[2][0] += xhi.x * wv.x; acc[2][1] += xhi.x * wv.y; acc[2][2] += xhi.x * wv.z; acc[2][3] += xhi.x * wv.w;
            acc[3][0] += xhi.y * wv.x; acc[3][1] += xhi.y * wv.y; acc[3][2] += xhi.y * wv.z; acc[3][3] += xhi.y * wv.w;
            if (has_proj) {
                float xp = xs[bi][j][prow];
                float4 wp = *(float4*)&ws[bi][j][64 + pc4 * 4];
                accp[0] += xp * wp.x; accp[1] += xp * wp.y;
                accp[2] += xp * wp.z; accp[3] += xp * wp.w;
            }
        }
        if (kc < 7) WRITE_LDS((kc + 1) & 1);
        __syncthreads();
    }
#undef ISSUE_LOADS
#undef WRITE_LDS

    // V epilogue
    {
        int d0 = cg * 64 + c0;
        float4 bv = *(const float4*)(b_value + d0);
#pragma unroll
        for (int i = 0; i < 4; i++) {
            size_t o = ((size_t)(b * L + row0 + r0 + i)) * D + d0;
            *(float4*)(V + o) = make_float4(acc[i][0] + bv.x, acc[i][1] + bv.y,
                                            acc[i][2] + bv.z, acc[i][3] + bv.w);
        }
    }
    if (!has_proj) return;
#pragma unroll
    for (int e = 0; e < 4; e++) zbuf[prow][pc4 * 4 + e] = tanhf(accp[e]) * PI_F;
    __syncthreads();
    // phasor epilogue: 64 rows x 4 threads; thread handles 4 cols + joint plane q
    {
        int tt = tid >> 2, q = tid & 3;
        size_t bt = (size_t)(b * L + row0 + tt);
        if (cg == 0) {
            float* fp = fk + bt * 40;
#pragma unroll
            for (int e = 0; e < 4; e++) {
                int col = q * 4 + e;
                float si, co; sincosf(zbuf[tt][col], &si, &co);
                fp[2 * col] = co; fp[2 * col + 1] = si;
            }
            float zs = zbuf[tt][q] + zbuf[tt][4 + q] + zbuf[tt][8 + q] + zbuf[tt][12 + q];
            float si, co; sincosf(zs, &si, &co);
            fp[32 + 2 * q] = co; fp[33 + 2 * q] = si;
        } else {
            float sw0 = set_weights[0], sw1 = set_weights[1], sw2 = set_weights[2], sw3 = set_weights[3];
            float mx = fmaxf(fmaxf(sw0, sw1), fmaxf(sw2, sw3));
            float e0 = expf(sw0 - mx), e1 = expf(sw1 - mx), e2 = expf(sw2 - mx), e3 = expf(sw3 - mx);
            float esum = e0 + e1 + e2 + e3;
            float wsoft[4] = {e0 / esum, e1 / esum, e2 / esum, e3 / esum};
            float* fp = fq + bt * 40;
#pragma unroll
            for (int e = 0; e < 4; e++) {
                int col = q * 4 + e;
                float si, co; sincosf(zbuf[tt][col], &si, &co);
                float sc = 0.1f * wsoft[col >> 2];   // 0.5 * w_s / (NSETS+1)
                fp[2 * col] = sc * co; fp[2 * col + 1] = sc * si;
            }
            float zs = zbuf[tt][q] + zbuf[tt][4 + q] + zbuf[tt][8 + q] + zbuf[tt][12 + q];
            float si, co; sincosf(zs, &si, &co);
            fp[32 + 2 * q] = 0.1f * co; fp[33 + 2 * q] = 0.1f * si;
        }
    }
}

// -------- fused gate: block-wide exclusive scan of jk + gate + scale fk ---------
__global__ __launch_bounds__(1024) void gate_kernel(
    float* __restrict__ fk,
    const float* __restrict__ surprise_scale, const float* __restrict__ surprise_bias,
    const float* __restrict__ resonance_scale, const float* __restrict__ resonance_threshold) {
    int b = blockIdx.x;
    int tid = threadIdx.x;
    __shared__ float scan[1024][8];
    float j0[8], j1[8], tot[8];
    float* fp0 = fk + ((size_t)(b * L + tid * 2)) * 40;
    float* fp1 = fk + ((size_t)(b * L + tid * 2 + 1)) * 40;
#pragma unroll
    for (int q = 0; q < 8; q++) {
        j0[q] = fp0[32 + q];
        j1[q] = fp1[32 + q];
        tot[q] = j0[q] + j1[q];
        scan[tid][q] = tot[q];
    }
    __syncthreads();
    for (int off = 1; off < 1024; off <<= 1) {
        float tmp[8];
        if (tid >= off) {
#pragma unroll
            for (int q = 0; q < 8; q++) tmp[q] = scan[tid - off][q];
        }
        __syncthreads();
        if (tid >= off) {
#pragma unroll
            for (int q = 0; q < 8; q++) scan[tid][q] += tmp[q];
        }
        __syncthreads();
    }
    float run[8];
#pragma unroll
    for (int q = 0; q < 8; q++) run[q] = scan[tid][q] - tot[q];   // exclusive
    float ss = surprise_scale[0], sb = surprise_bias[0];
    float scv = fminf(fmaxf(resonance_scale[0], 1.f), 20.f);
    float thv = fminf(fmaxf(resonance_threshold[0], 0.1f), 0.9f);
#pragma unroll
    for (int k = 0; k < 2; k++) {
        int t = tid * 2 + k;
        float* fp = k ? fp1 : fp0;
        float rmag = 0.25f * (sqrtf(run[0] * run[0] + run[1] * run[1]) +
                              sqrtf(run[2] * run[2] + run[3] * run[3]) +
                              sqrtf(run[4] * run[4] + run[5] * run[5]) +
                              sqrtf(run[6] * run[6] + run[7] * run[7]));
        float nres = rmag / sqrtf(fmaxf((float)t, 1.0f));
        float surprise = 0.5f * (1.0f - tanhf(scv * (nres - thv)));
        float gate = 1.0f / (1.0f + expf(-(ss * (surprise - 0.5f) + sb)));
#pragma unroll
        for (int q = 0; q < 8; q++) run[q] += (k ? j1[q] : j0[q]);
#pragma unroll
        for (int q = 0; q < 40; q++) fp[q] *= gate;
    }
}

// ---------------- 16-row sub-chunk sums of x, x^2 (LTM stats) -------------------
__global__ __launch_bounds__(256) void stats16_kernel(const float* __restrict__ x,
                                                      float* __restrict__ Sx16,
                                                      float* __restrict__ Sxx16) {
    int s = blockIdx.x, b = blockIdx.y;
    int d = threadIdx.x;
    float sx = 0.f, sxx = 0.f;
#pragma unroll
    for (int k = 0; k < 16; k++) {
        float v = x[((size_t)(b * L + s * 16 + k)) * D + d];
        sx += v; sxx += v * v;
    }
    Sx16[((size_t)(b * 128 + s)) * D + d] = sx;
    Sxx16[((size_t)(b * 128 + s)) * D + d] = sxx;
}

// ---------------- LTM phasor angles, 16 rows per block --------------------------
__global__ __launch_bounds__(256) void ltm_z_kernel(
    const float* __restrict__ x, const float* __restrict__ Sx16,
    const float* __restrict__ Sxx16, const float* __restrict__ Wt,
    float* __restrict__ czsz) {
    int s = blockIdx.x, b = blockIdx.y;
    int tid = threadIdx.x;
    __shared__ float xs[16][260], rms[16][260], rss[16][260];
    float a0 = 0.f, a1 = 0.f, a2 = 0.f, a3 = 0.f;
    float c0 = 0.f, c1 = 0.f, c2 = 0.f, c3 = 0.f;
    int sp = 0;
    for (; sp + 4 <= s; sp += 4) {
        a0 += Sx16[((size_t)(b * 128 + sp)) * D + tid];
        a1 += Sx16[((size_t)(b * 128 + sp + 1)) * D + tid];
        a2 += Sx16[((size_t)(b * 128 + sp + 2)) * D + tid];
        a3 += Sx16[((size_t)(b * 128 + sp + 3)) * D + tid];
        c0 += Sxx16[((size_t)(b * 128 + sp)) * D + tid];
        c1 += Sxx16[((size_t)(b * 128 + sp + 1)) * D + tid];
        c2 += Sxx16[((size_t)(b * 128 + sp + 2)) * D + tid];
        c3 += Sxx16[((size_t)(b * 128 + sp + 3)) * D + tid];
    }
    for (; sp < s; sp++) {
        a0 += Sx16[((size_t)(b * 128 + sp)) * D + tid];
        c0 += Sxx16[((size_t)(b * 128 + sp)) * D + tid];
    }
    float runx = (a0 + a1) + (a2 + a3), runxx = (c0 + c1) + (c2 + c3);
    for (int k = 0; k < 16; k++) {
        int tg = s * 16 + k;
        float xv = x[((size_t)(b * L + tg)) * D + tid];
        runx += xv; runxx += xv * xv;
        float n = (float)(tg + 1);
        float rm = runx / n;
        float rv = runxx / n - rm * rm;
        xs[k][tid] = xv; rms[k][tid] = rm;
        rss[k][tid] = sqrtf(fmaxf(rv, 1e-8f));
    }
    __syncthreads();
    int tl = tid & 15, p = tid >> 4;
    const float* W0 = Wt + p * 768;
    float u0 = 0.f, u1 = 0.f, u2 = 0.f;
#pragma unroll 4
    for (int j4 = 0; j4 < 64; j4++) {
        float4 xv = *(float4*)&xs[tl][j4 * 4];
        float4 wx = *(const float4*)(W0 + j4 * 4);
        float4 rv = *(float4*)&rms[tl][j4 * 4];
        float4 wr = *(const float4*)(W0 + 256 + j4 * 4);
        float4 sv = *(float4*)&rss[tl][j4 * 4];
        float4 wz = *(const float4*)(W0 + 512 + j4 * 4);
        u0 += xv.x * wx.x + xv.y * wx.y + xv.z * wx.z + xv.w * wx.w;
        u1 += rv.x * wr.x + rv.y * wr.y + rv.z * wr.z + rv.w * wr.w;
        u2 += sv.x * wz.x + sv.y * wz.y + sv.z * wz.z + sv.w * wz.w;
    }
    float z = tanhf(u0 + u1 + u2) * PI_F;
    float si, co; sincosf(z, &si, &co);
    int tg = s * 16 + tl;
    czsz[((size_t)(b * L + tg)) * 32 + p] = co;
    czsz[((size_t)(b * L + tg)) * 32 + 16 + p] = si;
}

// ------------- half-chunk outer-product sums Sh[b,c,h,f,d] (32-t halves) --------
// float4 staging from fk + interleaved posci.
__global__ __launch_bounds__(256) void outer_sums_kernel(
    const float* __restrict__ V, const float* __restrict__ fk,
    const float* __restrict__ posci, float* __restrict__ Sh) {
    int g = blockIdx.x >> 1, h = blockIdx.x & 1;
    int c = blockIdx.y;
    int b = blockIdx.z;
    int tid = threadIdx.x;
    __shared__ float Fk[32][40];
    int F0 = g * 36;
#pragma unroll
    for (int e = 0; e < 2; e++) {
        int idx = e * 256 + tid;     // 288 f4 = 32 rows x 9
        if (idx < 288) {
            int r = idx / 9, c4 = idx - r * 9;
            int tg = c * T + h * 32 + r;
            float4 v;
            if (g == 0) v = *(const float4*)(fk + ((size_t)(b * L + tg)) * 40 + c4 * 4);
            else if (c4 == 0) v = *(const float4*)(fk + ((size_t)(b * L + tg)) * 40 + 36);
            else v = *(const float4*)(posci + tg * 32 + (c4 - 1) * 4);
            *(float4*)&Fk[r][c4 * 4] = v;
        }
    }
    __syncthreads();
    float acc[36];
#pragma unroll
    for (int f = 0; f < 36; f++) acc[f] = 0.f;
    for (int t = 0; t < 32; t++) {
        float v = V[((size_t)(b * L + c * T + h * 32 + t)) * D + tid];
#pragma unroll
        for (int f4 = 0; f4 < 9; f4++) {
            float4 fkv = *(float4*)&Fk[t][f4 * 4];
            acc[f4 * 4 + 0] += fkv.x * v;
            acc[f4 * 4 + 1] += fkv.y * v;
            acc[f4 * 4 + 2] += fkv.z * v;
            acc[f4 * 4 + 3] += fkv.w * v;
        }
    }
    for (int f = 0; f < 36; f++)
        Sh[((((size_t)(b * C + c)) * 2 + h) * F + F0 + f) * D + tid] = acc[f];
}

// ------- exclusive prefix over chunks, combining half-chunk sums ---------------
__global__ __launch_bounds__(256) void prefix_kernel(const float* __restrict__ Sh,
                                                     float* __restrict__ S) {
    int bf = blockIdx.x;
    int b = bf / F, f = bf % F;
    int d = threadIdx.x;
    float v0[C], v1[C];
#pragma unroll
    for (int c = 0; c < C; c++) {
        v0[c] = Sh[((((size_t)(b * C + c)) * 2 + 0) * F + f) * D + d];
        v1[c] = Sh[((((size_t)(b * C + c)) * 2 + 1) * F + f) * D + d];
    }
    float run = 0.f;
#pragma unroll
    for (int c = 0; c < C; c++) {
        S[(((size_t)(b * C + c)) * F + f) * D + d] = run;
        run += v0[c] + v1[c];
    }
}

// ---------------- intra (fused score): ret = Fq·M + A·V -------------------------
// grid (8 = 4 tg x 2 dh, 32 c, B) = 1024 blocks; float4 staging via fk+posci.
__global__ __launch_bounds__(256) void intra_kernel(
    const float* __restrict__ V, float* __restrict__ ret,
    const float* __restrict__ fk, const float* __restrict__ fq,
    const float* __restrict__ posci, const float* __restrict__ Mexc,
    const float* __restrict__ pos_weight) {
    int tg = blockIdx.x >> 1, dh = blockIdx.x & 1;
    int c = blockIdx.y, b = blockIdx.z;
    int tid = threadIdx.x;
    int t0 = tg * 16;
    __shared__ float Fk[64][76];
    __shared__ float Fq[16][76];
    __shared__ float As[16][68];
    float posq = 0.5f / (1.0f + expf(-pos_weight[0]));
    // stage Fk: 64 rows x 18 f4 (10 from fk, 8 from posci)
#pragma unroll
    for (int e = 0; e < 5; e++) {
        int idx = e * 256 + tid;
        if (idx < 1152) {
            int r = idx / 18, c4 = idx - r * 18;
            int tgl = c * T + r;
            float4 v;
            if (c4 < 10) v = *(const float4*)(fk + ((size_t)(b * L + tgl)) * 40 + c4 * 4);
            else v = *(const float4*)(posci + tgl * 32 + (c4 - 10) * 4);
            *(float4*)&Fk[r][c4 * 4] = v;
        }
    }
    // stage Fq: 16 rows x 18 f4; pos part scaled by posq
#pragma unroll
    for (int e = 0; e < 2; e++) {
        int idx = e * 256 + tid;
        if (idx < 288) {
            int r = idx / 18, c4 = idx - r * 18;
            int tgl = c * T + t0 + r;
            float4 v;
            if (c4 < 10) v = *(const float4*)(fq + ((size_t)(b * L + tgl)) * 40 + c4 * 4);
            else {
                v = *(const float4*)(posci + tgl * 32 + (c4 - 10) * 4);
                v.x *= posq; v.y *= posq; v.z *= posq; v.w *= posq;
            }
            *(float4*)&Fq[r][c4 * 4] = v;
        }
    }
    __syncthreads();
    // A[r][k]: 16 x 64, 4 k's per thread; hoisted Fq fragment, mask after
    {
        int r = tid >> 4, k0 = (tid & 15) * 4;
        int tglob = t0 + r;
        float a0 = 0.f, a1 = 0.f, a2 = 0.f, a3 = 0.f;
#pragma unroll
        for (int f4 = 0; f4 < 18; f4++) {
            float4 q = *(float4*)&Fq[r][f4 * 4];
            float4 k0v = *(float4*)&Fk[k0 + 0][f4 * 4];
            float4 k1v = *(float4*)&Fk[k0 + 1][f4 * 4];
            float4 k2v = *(float4*)&Fk[k0 + 2][f4 * 4];
            float4 k3v = *(float4*)&Fk[k0 + 3][f4 * 4];
            a0 += q.x * k0v.x + q.y * k0v.y + q.z * k0v.z + q.w * k0v.w;
            a1 += q.x * k1v.x + q.y * k1v.y + q.z * k1v.z + q.w * k1v.w;
            a2 += q.x * k2v.x + q.y * k2v.y + q.z * k2v.z + q.w * k2v.w;
            a3 += q.x * k3v.x + q.y * k3v.y + q.z * k3v.z + q.w * k3v.w;
        }
        float4 av = make_float4((k0 + 0 <= tglob) ? a0 : 0.f, (k0 + 1 <= tglob) ? a1 : 0.f,
                                (k0 + 2 <= tglob) ? a2 : 0.f, (k0 + 3 <= tglob) ? a3 : 0.f);
        *(float4*)&As[tid >> 4][k0] = av;
    }
    __syncthreads();
    // main: thread owns column d, 8 rows; stream M then V from global
    int dl = tid & 127, rowg = tid >> 7;
    int d = dh * 128 + dl;
    int r0 = rowg * 8;
    float acc[8];
#pragma unroll
    for (int i = 0; i < 8; i++) acc[i] = 0.f;
    const float* Mp = Mexc + (((size_t)(b * C + c)) * F) * D + d;
#pragma unroll 8
    for (int f = 0; f < F; f++) {
        float m = Mp[(size_t)f * D];
#pragma unroll
        for (int i = 0; i < 8; i++) acc[i] += Fq[r0 + i][f] * m;
    }
    const float* Vp = V + ((size_t)(b * L + c * T)) * D + d;
    int kmax = t0 + 16;
#pragma unroll 8
    for (int k = 0; k < kmax; k++) {
        float v = Vp[(size_t)k * D];
#pragma unroll
        for (int i = 0; i < 8; i++) acc[i] += As[r0 + i][k] * v;
    }
    float* Rp = ret + ((size_t)(b * L + c * T + t0 + r0)) * D + d;
#pragma unroll
    for (int i = 0; i < 8; i++) Rp[(size_t)i * D] = acc[i];
}

// ---------------- hprep: hn = LN((ret + lcoef*pers)/nrm)*gamma + beta -----------
__global__ __launch_bounds__(256) void hprep_kernel(
    const float* __restrict__ retp, const float* __restrict__ czsz,
    const float* __restrict__ ltm_mem, const float* __restrict__ ltm_count,
    const float* __restrict__ ltm_weight, const float* __restrict__ ln_gamma,
    const float* __restrict__ ln_beta, float* __restrict__ hn) {
    int rc = blockIdx.x;
    int b  = blockIdx.y;
    int row0 = rc * 16;
    int tid = threadIdx.x;
    __shared__ float hb[16][260];    // 260%32==4 -> stats stride-16 is 2-way (free)
    __shared__ float cs[16][33];
    __shared__ float part1[16][17], part2[16][17];
    __shared__ float mu[16], rsig[16];
    float lsig = 1.f / (1.f + expf(-ltm_weight[0]));
    float pnorm = sqrtf(fmaxf(ltm_count[0], 1.f) * (float)LTMP);
    float lcoef = lsig / pnorm;
    float Mre[16], Mim[16];
#pragma unroll
    for (int p = 0; p < 16; p++) {
        Mre[p] = ltm_mem[(p * D + tid) * 2];
        Mim[p] = ltm_mem[(p * D + tid) * 2 + 1];
    }
    float gam = ln_gamma[tid], bet = ln_beta[tid];
#pragma unroll
    for (int e = 0; e < 2; e++) {
        int idx = e * 256 + tid;     // 512 = 16 rows x 32
        int t = idx >> 5, q = idx & 31;
        cs[t][q] = czsz[((size_t)(b * L + row0 + t)) * 32 + q];
    }
    __syncthreads();
#pragma unroll 4
    for (int t = 0; t < 16; t++) {
        int tg = row0 + t;
        float pers = 0.f;
#pragma unroll
        for (int p = 0; p < 16; p++) pers += Mre[p] * cs[t][p] + Mim[p] * cs[t][16 + p];
        float rv = retp[((size_t)(b * L + tg)) * D + tid];
        hb[t][tid] = (rv + lcoef * pers) / (2.0f * sqrtf((float)(tg + 1)));
    }
    __syncthreads();
    {
        int row = tid & 15, e = tid >> 4;
        float s1 = 0.f, s2 = 0.f;
#pragma unroll
        for (int k = 0; k < 16; k++) {
            float v = hb[row][e + 16 * k];
            s1 += v; s2 += v * v;
        }
        part1[row][e] = s1; part2[row][e] = s2;
    }
    __syncthreads();
    if (tid < 16) {
        float s1 = 0.f, s2 = 0.f;
#pragma unroll
        for (int e = 0; e < 16; e++) { s1 += part1[tid][e]; s2 += part2[tid][e]; }
        float m = s1 / 256.f;
        mu[tid] = m;
        rsig[tid] = rsqrtf(fmaxf(s2 / 256.f - m * m, 0.f) + 1e-5f);
    }
    __syncthreads();
#pragma unroll 4
    for (int t = 0; t < 16; t++)
        hn[((size_t)(b * L + row0 + t)) * D + tid] =
            (hb[t][tid] - mu[t]) * rsig[t] * gam + bet;
}

// ---------------- gemm_out: out = x + hn @ w_out + b_out ------------------------
__global__ __launch_bounds__(256) void gemm_out_kernel(
    const float* __restrict__ hn, const float* __restrict__ w_out,
    const float* __restrict__ b_out, const float* __restrict__ x,
    float* __restrict__ out) {
    int cg = blockIdx.x;
    int rc = blockIdx.y;
    int b  = blockIdx.z;
    int row0 = rc * 64;
    int tid = threadIdx.x;
    __shared__ float hs[2][32][74];
    __shared__ float wo[2][32][68];
    int rg = tid >> 4, cgi = tid & 15;
    int r0 = rg * 4, c0 = cgi * 4;
    float acc[4][4];
#pragma unroll
    for (int i = 0; i < 4; i++)
#pragma unroll
        for (int e = 0; e < 4; e++) acc[i][e] = 0.f;
    int rrA = tid >> 3, k4A = tid & 7;
    int jA = tid >> 4, c4A = tid & 15;
    float4 hr0, hr1, wr0, wr1;

#define ISSUE_LOADS(kb_)                                                            \
    {                                                                               \
        hr0 = *(const float4*)(hn + ((size_t)(b * L + row0 + rrA)) * D + (kb_) + k4A * 4);      \
        hr1 = *(const float4*)(hn + ((size_t)(b * L + row0 + 32 + rrA)) * D + (kb_) + k4A * 4); \
        wr0 = *(const float4*)(w_out + (size_t)((kb_) + jA) * D + cg * 64 + c4A * 4);           \
        wr1 = *(const float4*)(w_out + (size_t)((kb_) + 16 + jA) * D + cg * 64 + c4A * 4);      \
    }
#define WRITE_LDS(bi)                                                               \
    {                                                                               \
        const float* hp0 = (const float*)&hr0;                                      \
        const float* hp1 = (const float*)&hr1;                                      \
        _Pragma("unroll")                                                           \
        for (int u = 0; u < 4; u++) {                                               \
            hs[bi][k4A * 4 + u][rrA] = hp0[u];                                      \
            hs[bi][k4A * 4 + u][32 + rrA] = hp1[u];                                 \
        }                                                                           \
        *(float4*)&wo[bi][jA][c4A * 4] = wr0;                                       \
        *(float4*)&wo[bi][16 + jA][c4A * 4] = wr1;                                  \
    }

    ISSUE_LOADS(0);
    WRITE_LDS(0);
    __syncthreads();
    for (int kc = 0; kc < 8; kc++) {
        if (kc < 7) ISSUE_LOADS((kc + 1) * 32);
        int bi = kc & 1;
#pragma unroll 8
        for (int j = 0; j < 32; j++) {
            float2 xlo = *(float2*)&hs[bi][j][r0];
            float2 xhi = *(float2*)&hs[bi][j][r0 + 2];
            float4 wv = *(float4*)&wo[bi][j][c0];
            acc[0][0] += xlo.x * wv.x; acc[0][1] += xlo.x * wv.y; acc[0][2] += xlo.x * wv.z; acc[0][3] += xlo.x * wv.w;
            acc[1][0] += xlo.y * wv.x; acc[1][1] += xlo.y * wv.y; acc[1][2] += xlo.y * wv.z; acc[1][3] += xlo.y * wv.w;
            acc[2][0] += xhi.x * wv.x; acc[2][1] += xhi.x * wv.y; acc[2][2] += xhi.x * wv.z; acc[2][3] += xhi.x * wv.w;
            acc[3][0] += xhi.y * wv.x; acc[3][1] += xhi.y * wv.y; acc[3][2] += xhi.y * wv.z; acc[3][3] += xhi.y * wv.w;
        }
        if (kc < 7) WRITE_LDS((kc + 1) & 1);
        __syncthreads();
    }
#undef ISSUE_LOADS
#undef WRITE_LDS
    {
        int d0 = cg * 64 + c0;
        float4 bo = *(const float4*)(b_out + d0);
#pragma unroll
        for (int i = 0; i < 4; i++) {
            size_t o = ((size_t)(b * L + row0 + r0 + i)) * D + d0;
            float4 xa = *(const float4*)(x + o);
            *(float4*)(out + o) = make_float4(xa.x + acc[i][0] + bo.x, xa.y + acc[i][1] + bo.y,
                                              xa.z + acc[i][2] + bo.z, xa.w + acc[i][3] + bo.w);
        }
    }
}

extern "C" void kernel_launch(void* const* d_in, const int* in_sizes, int n_in,
                              void* d_out, int out_size, void* d_ws, size_t ws_size,
                              hipStream_t stream) {
    (void)in_sizes; (void)n_in; (void)out_size; (void)ws_size;
    const float* x            = (const float*)d_in[0];
    const float* key_proj     = (const float*)d_in[1];
    const float* query_proj   = (const float*)d_in[2];
    const float* ltm_key_proj = (const float*)d_in[3];
    const float* pos_freqs    = (const float*)d_in[4];
    const float* w_value      = (const float*)d_in[5];
    const float* b_value      = (const float*)d_in[6];
    const float* ln_gamma     = (const float*)d_in[9];
    const float* ln_beta      = (const float*)d_in[10];
    const float* w_out        = (const float*)d_in[11];
    const float* b_out        = (const float*)d_in[12];
    const float* set_weights  = (const float*)d_in[13];
    const float* pos_weight   = (const float*)d_in[14];
    const float* surprise_scale      = (const float*)d_in[15];
    const float* surprise_bias       = (const float*)d_in[16];
    const float* resonance_scale     = (const float*)d_in[17];
    const float* resonance_threshold = (const float*)d_in[18];
    const float* ltm_weight   = (const float*)d_in[19];
    const float* ltm_mem      = (const float*)d_in[20];
    const float* ltm_count    = (const float*)d_in[21];
    float* out = (float*)d_out;

    float* ws = (float*)d_ws;
    size_t off = 0;
    float* V     = ws + off; off += (size_t)B * L * D;   // reused as hn after intra
    float* ret   = ws + off; off += (size_t)B * L * D;
    float* fk    = ws + off; off += (size_t)B * L * 40;
    float* fq    = ws + off; off += (size_t)B * L * 40;
    float* posci = ws + off; off += (size_t)L * 32;
    float* Sx16  = ws + off; off += (size_t)B * 128 * D;
    float* Sxx16 = ws + off; off += (size_t)B * 128 * D;
    float* czsz  = ws + off; off += (size_t)B * L * 32;
    float* Sh    = ws + off; off += (size_t)B * C * 2 * F * D;   // half-chunk sums
    float* S     = ws + off; off += (size_t)B * C * F * D;       // exclusive prefix
    float* Wt    = ws + off; off += (size_t)16 * 768;
    float* hn = V;   // V retired after intra reads it

    pos_kernel<<<dim3(176), 256, 0, stream>>>(pos_freqs, ltm_key_proj, posci, Wt);
    featurize_kernel<<<dim3(4, 32, B), 256, 0, stream>>>(x, key_proj, query_proj, w_value,
                                                         b_value, set_weights, V, fk, fq);
    gate_kernel<<<dim3(B), 1024, 0, stream>>>(fk, surprise_scale, surprise_bias,
                                              resonance_scale, resonance_threshold);
    stats16_kernel<<<dim3(128, B), 256, 0, stream>>>(x, Sx16, Sxx16);
    ltm_z_kernel<<<dim3(128, B), 256, 0, stream>>>(x, Sx16, Sxx16, Wt, czsz);
    outer_sums_kernel<<<dim3(4, C, B), 256, 0, stream>>>(V, fk, posci, Sh);
    prefix_kernel<<<dim3(B * F), 256, 0, stream>>>(Sh, S);
    intra_kernel<<<dim3(8, C, B), 256, 0, stream>>>(V, ret, fk, fq, posci, S, pos_weight);
    hprep_kernel<<<dim3(128, B), 256, 0, stream>>>(ret, czsz, ltm_mem, ltm_count, ltm_weight,
                                                   ln_gamma, ln_beta, hn);
    gemm_out_kernel<<<dim3(4, 32, B), 256, 0, stream>>>(hn, w_out, b_out, x, out);
}

// Round 12
// 246.191 us; speedup vs baseline: 1.1455x; 1.0726x over previous
//
#include <hip/hip_runtime.h>
#include <math.h>

#define B 4
#define L 2048
#define D 256
#define POSP 16
#define LTMP 16
#define T 64
#define C 32
#define F 72
#define PI_F 3.14159274101257324f
#define TWO_PI_D 6.283185307179586476925286766559

// -- prep: pos phasors (interleaved) + Wt transpose + 16-row x/x^2 sums ----------
// grid 688: [0,128) pos, [128,176) Wt, [176,688) stats16 (512 = 128 s-chunks x B)
__global__ __launch_bounds__(256) void prep_kernel(const float* __restrict__ pos_freqs,
                                                   const float* __restrict__ lkp,
                                                   const float* __restrict__ x,
                                                   float* __restrict__ posci,
                                                   float* __restrict__ Wt,
                                                   float* __restrict__ Sx16,
                                                   float* __restrict__ Sxx16) {
    int bid = blockIdx.x;
    int tid = threadIdx.x;
    if (bid < 128) {
        int idx = bid * 256 + tid;
        int t = idx >> 4, p = idx & 15;
        float a = (float)t * pos_freqs[p];   // replicate numpy op order in fp32
        float th = (a * 2.0f) * PI_F;
        double r = fmod((double)th, TWO_PI_D);
        posci[t * 32 + 2 * p] = (float)cos(r);
        posci[t * 32 + 2 * p + 1] = (float)sin(r);
    } else if (bid < 176) {
        int i2 = (bid - 128) * 256 + tid;
        if (i2 < 16 * 768) {
            int p = i2 / 768, j = i2 - p * 768;
            Wt[i2] = lkp[j * 16 + p];
        }
    } else {
        int sb = bid - 176;          // 0..511
        int s = sb & 127, b = sb >> 7;
        float sx = 0.f, sxx = 0.f;
#pragma unroll
        for (int k = 0; k < 16; k++) {
            float v = x[((size_t)(b * L + s * 16 + k)) * D + tid];
            sx += v; sxx += v * v;
        }
        Sx16[((size_t)(b * 128 + s)) * D + tid] = sx;
        Sxx16[((size_t)(b * 128 + s)) * D + tid] = sxx;
    }
}

// ---------------- featurize: fused GEMM x @ [w_value | key_proj | query_proj] ---
// grid (4 col-groups of 64, 32 row-chunks of 64, B); 256 thr; 4x4 micro-tile;
// x staged TRANSPOSED with row stride 74 (conflict-free); double-buffered.
// cg0 epilogue also reduces ungated jk -> 2 chunk partials (for gate scan).
__global__ __launch_bounds__(256) void featurize_kernel(
    const float* __restrict__ x, const float* __restrict__ key_proj,
    const float* __restrict__ query_proj, const float* __restrict__ w_value,
    const float* __restrict__ b_value, const float* __restrict__ set_weights,
    float* __restrict__ V, float* __restrict__ fk, float* __restrict__ fq,
    float* __restrict__ partial) {
    int cg = blockIdx.x;
    int rc = blockIdx.y;
    int b  = blockIdx.z;
    int row0 = rc * 64;
    int tid = threadIdx.x;
    __shared__ float xs[2][32][74];   // [buf][k][row] transposed x, stride 74
    __shared__ float ws[2][32][84];   // [buf][k][64 V-cols + 16 proj cols]
    __shared__ float zbuf[64][20];
    __shared__ float jkv[64][9];
    const bool has_proj = (cg < 2);
    const float* proj = (cg == 0) ? key_proj : query_proj;
    int rg = tid >> 4, cgi = tid & 15;
    int r0 = rg * 4, c0 = cgi * 4;
    int prow = tid >> 2, pc4 = tid & 3;
    float acc[4][4], accp[4];
#pragma unroll
    for (int i = 0; i < 4; i++) {
#pragma unroll
        for (int e = 0; e < 4; e++) acc[i][e] = 0.f;
        accp[i] = 0.f;
    }
    int rrA = tid >> 3, k4A = tid & 7;     // x stage mapping
    int jA = tid >> 4, c4A = tid & 15;     // w stage mapping
    float4 xr0, xr1, wr0, wr1, prr;

#define ISSUE_LOADS(kb_)                                                            \
    {                                                                               \
        xr0 = *(const float4*)(x + ((size_t)(b * L + row0 + rrA)) * D + (kb_) + k4A * 4);      \
        xr1 = *(const float4*)(x + ((size_t)(b * L + row0 + 32 + rrA)) * D + (kb_) + k4A * 4); \
        wr0 = *(const float4*)(w_value + (size_t)((kb_) + jA) * D + cg * 64 + c4A * 4);        \
        wr1 = *(const float4*)(w_value + (size_t)((kb_) + 16 + jA) * D + cg * 64 + c4A * 4);   \
        if (has_proj && tid < 128)                                                  \
            prr = *(const float4*)(proj + (size_t)((kb_) + (tid >> 2)) * 16 + (tid & 3) * 4);  \
    }
#define WRITE_LDS(bi)                                                               \
    {                                                                               \
        const float* xp0 = (const float*)&xr0;                                      \
        const float* xp1 = (const float*)&xr1;                                      \
        _Pragma("unroll")                                                           \
        for (int u = 0; u < 4; u++) {                                               \
            xs[bi][k4A * 4 + u][rrA] = xp0[u];                                      \
            xs[bi][k4A * 4 + u][32 + rrA] = xp1[u];                                 \
        }                                                                           \
        *(float4*)&ws[bi][jA][c4A * 4] = wr0;                                       \
        *(float4*)&ws[bi][16 + jA][c4A * 4] = wr1;                                  \
        if (has_proj && tid < 128)                                                  \
            *(float4*)&ws[bi][tid >> 2][64 + (tid & 3) * 4] = prr;                  \
    }

    ISSUE_LOADS(0);
    WRITE_LDS(0);
    __syncthreads();
    for (int kc = 0; kc < 8; kc++) {
        if (kc < 7) ISSUE_LOADS((kc + 1) * 32);
        int bi = kc & 1;
#pragma unroll 8
        for (int j = 0; j < 32; j++) {
            float2 xlo = *(float2*)&xs[bi][j][r0];
            float2 xhi = *(float2*)&xs[bi][j][r0 + 2];
            float4 wv = *(float4*)&ws[bi][j][c0];
            acc[0][0] += xlo.x * wv.x; acc[0][1] += xlo.x * wv.y; acc[0][2] += xlo.x * wv.z; acc[0][3] += xlo.x * wv.w;
            acc[1][0] += xlo.y * wv.x; acc[1][1] += xlo.y * wv.y; acc[1][2] += xlo.y * wv.z; acc[1][3] += xlo.y * wv.w;
            acc[2][0] += xhi.x * wv.x; acc[2][1] += xhi.x * wv.y; acc[2][2] += xhi.x * wv.z; acc[2][3] += xhi.x * wv.w;
            acc[3][0] += xhi.y * wv.x; acc[3][1] += xhi.y * wv.y; acc[3][2] += xhi.y * wv.z; acc[3][3] += xhi.y * wv.w;
            if (has_proj) {
                float xp = xs[bi][j][prow];
                float4 wp = *(float4*)&ws[bi][j][64 + pc4 * 4];
                accp[0] += xp * wp.x; accp[1] += xp * wp.y;
                accp[2] += xp * wp.z; accp[3] += xp * wp.w;
            }
        }
        if (kc < 7) WRITE_LDS((kc + 1) & 1);
        __syncthreads();
    }
#undef ISSUE_LOADS
#undef WRITE_LDS

    // V epilogue
    {
        int d0 = cg * 64 + c0;
        float4 bv = *(const float4*)(b_value + d0);
#pragma unroll
        for (int i = 0; i < 4; i++) {
            size_t o = ((size_t)(b * L + row0 + r0 + i)) * D + d0;
            *(float4*)(V + o) = make_float4(acc[i][0] + bv.x, acc[i][1] + bv.y,
                                            acc[i][2] + bv.z, acc[i][3] + bv.w);
        }
    }
    if (!has_proj) return;
#pragma unroll
    for (int e = 0; e < 4; e++) zbuf[prow][pc4 * 4 + e] = tanhf(accp[e]) * PI_F;
    __syncthreads();
    // phasor epilogue: 64 rows x 4 threads; thread handles 4 cols + joint plane q
    {
        int tt = tid >> 2, q = tid & 3;
        size_t bt = (size_t)(b * L + row0 + tt);
        if (cg == 0) {
            float* fp = fk + bt * 40;
#pragma unroll
            for (int e = 0; e < 4; e++) {
                int col = q * 4 + e;
                float si, co; sincosf(zbuf[tt][col], &si, &co);
                fp[2 * col] = co; fp[2 * col + 1] = si;
            }
            float zs = zbuf[tt][q] + zbuf[tt][4 + q] + zbuf[tt][8 + q] + zbuf[tt][12 + q];
            float si, co; sincosf(zs, &si, &co);
            fp[32 + 2 * q] = co; fp[33 + 2 * q] = si;
            jkv[tt][2 * q] = co; jkv[tt][2 * q + 1] = si;
        } else {
            float sw0 = set_weights[0], sw1 = set_weights[1], sw2 = set_weights[2], sw3 = set_weights[3];
            float mx = fmaxf(fmaxf(sw0, sw1), fmaxf(sw2, sw3));
            float e0 = expf(sw0 - mx), e1 = expf(sw1 - mx), e2 = expf(sw2 - mx), e3 = expf(sw3 - mx);
            float esum = e0 + e1 + e2 + e3;
            float wsoft[4] = {e0 / esum, e1 / esum, e2 / esum, e3 / esum};
            float* fp = fq + bt * 40;
#pragma unroll
            for (int e = 0; e < 4; e++) {
                int col = q * 4 + e;
                float si, co; sincosf(zbuf[tt][col], &si, &co);
                float sc = 0.1f * wsoft[col >> 2];   // 0.5 * w_s / (NSETS+1)
                fp[2 * col] = sc * co; fp[2 * col + 1] = sc * si;
            }
            float zs = zbuf[tt][q] + zbuf[tt][4 + q] + zbuf[tt][8 + q] + zbuf[tt][12 + q];
            float si, co; sincosf(zs, &si, &co);
            fp[32 + 2 * q] = 0.1f * co; fp[33 + 2 * q] = 0.1f * si;
        }
    }
    __syncthreads();
    if (cg == 0) {   // reduce ungated jk over two 32-row halves -> 2 chunk partials
        int h = tid >> 7, idxr = tid & 127;
        int rr2 = idxr >> 3, ch = idxr & 7;
#pragma unroll
        for (int s2 = 16; s2 >= 1; s2 >>= 1) {
            if (rr2 < s2) jkv[h * 32 + rr2][ch] += jkv[h * 32 + rr2 + s2][ch];
            __syncthreads();
        }
        if (rr2 == 0) partial[((size_t)(b * 64 + rc * 2 + h)) * 8 + ch] = jkv[h * 32][ch];
    }
}

// ---------------- gate scan phase 2: exclusive scan of 64 chunk partials --------
__global__ __launch_bounds__(512) void gs_scan_kernel(const float* __restrict__ partial,
                                                      float* __restrict__ chunkoff) {
    int b = blockIdx.x;
    int tid = threadIdx.x;   // 512 = 64 chunks x 8 ch
    int c = tid >> 3, ch = tid & 7;
    __shared__ float sc_[64][9];
    float own = partial[((size_t)(b * 64 + c)) * 8 + ch];
    sc_[c][ch] = own;
    __syncthreads();
    for (int off = 1; off < 64; off <<= 1) {
        float v = 0.f;
        if (c >= off) v = sc_[c - off][ch];
        __syncthreads();
        if (c >= off) sc_[c][ch] += v;
        __syncthreads();
    }
    chunkoff[((size_t)(b * 64 + c)) * 8 + ch] = sc_[c][ch] - own;
}

// ---------------- gate scan phase 3: local scan, gate, scale fk -----------------
__global__ __launch_bounds__(256) void gs_apply_kernel(
    float* __restrict__ fk, const float* __restrict__ chunkoff,
    const float* __restrict__ surprise_scale, const float* __restrict__ surprise_bias,
    const float* __restrict__ resonance_scale, const float* __restrict__ resonance_threshold) {
    int rc = blockIdx.x, b = blockIdx.y;
    int tid = threadIdx.x;
    int t = tid >> 3, ch = tid & 7;
    __shared__ float sc_[32][9];
    __shared__ float gbuf[32];
    float* fp = fk + ((size_t)(b * L + rc * 32 + t)) * 40;
    float own = fp[32 + ch];
    sc_[t][ch] = own;
    __syncthreads();
    for (int off = 1; off < 32; off <<= 1) {
        float v = 0.f;
        if (t >= off) v = sc_[t - off][ch];
        __syncthreads();
        if (t >= off) sc_[t][ch] += v;
        __syncthreads();
    }
    float run = chunkoff[((size_t)(b * 64 + rc)) * 8 + ch] + sc_[t][ch] - own;
    __syncthreads();
    sc_[t][ch] = run;
    __syncthreads();
    if (tid < 32) {
        int tg = rc * 32 + tid;
        float r0 = sc_[tid][0], r1 = sc_[tid][1], r2 = sc_[tid][2], r3 = sc_[tid][3];
        float r4 = sc_[tid][4], r5 = sc_[tid][5], r6 = sc_[tid][6], r7 = sc_[tid][7];
        float rmag = 0.25f * (sqrtf(r0 * r0 + r1 * r1) + sqrtf(r2 * r2 + r3 * r3) +
                              sqrtf(r4 * r4 + r5 * r5) + sqrtf(r6 * r6 + r7 * r7));
        float scv = fminf(fmaxf(resonance_scale[0], 1.f), 20.f);
        float thv = fminf(fmaxf(resonance_threshold[0], 0.1f), 0.9f);
        float nres = rmag / sqrtf(fmaxf((float)tg, 1.0f));
        float surprise = 0.5f * (1.0f - tanhf(scv * (nres - thv)));
        gbuf[tid] = 1.0f / (1.0f + expf(-(surprise_scale[0] * (surprise - 0.5f) + surprise_bias[0])));
    }
    __syncthreads();
    float gv = gbuf[t];
#pragma unroll
    for (int e = 0; e < 5; e++) fp[ch * 5 + e] *= gv;
}

// ---------------- LTM phasor angles, 16 rows per block --------------------------
__global__ __launch_bounds__(256) void ltm_z_kernel(
    const float* __restrict__ x, const float* __restrict__ Sx16,
    const float* __restrict__ Sxx16, const float* __restrict__ Wt,
    float* __restrict__ czsz) {
    int s = blockIdx.x, b = blockIdx.y;
    int tid = threadIdx.x;
    __shared__ float xs[16][260], rms[16][260], rss[16][260];
    float a0 = 0.f, a1 = 0.f, a2 = 0.f, a3 = 0.f;
    float c0 = 0.f, c1 = 0.f, c2 = 0.f, c3 = 0.f;
    int sp = 0;
    for (; sp + 4 <= s; sp += 4) {
        a0 += Sx16[((size_t)(b * 128 + sp)) * D + tid];
        a1 += Sx16[((size_t)(b * 128 + sp + 1)) * D + tid];
        a2 += Sx16[((size_t)(b * 128 + sp + 2)) * D + tid];
        a3 += Sx16[((size_t)(b * 128 + sp + 3)) * D + tid];
        c0 += Sxx16[((size_t)(b * 128 + sp)) * D + tid];
        c1 += Sxx16[((size_t)(b * 128 + sp + 1)) * D + tid];
        c2 += Sxx16[((size_t)(b * 128 + sp + 2)) * D + tid];
        c3 += Sxx16[((size_t)(b * 128 + sp + 3)) * D + tid];
    }
    for (; sp < s; sp++) {
        a0 += Sx16[((size_t)(b * 128 + sp)) * D + tid];
        c0 += Sxx16[((size_t)(b * 128 + sp)) * D + tid];
    }
    float runx = (a0 + a1) + (a2 + a3), runxx = (c0 + c1) + (c2 + c3);
    for (int k = 0; k < 16; k++) {
        int tg = s * 16 + k;
        float xv = x[((size_t)(b * L + tg)) * D + tid];
        runx += xv; runxx += xv * xv;
        float n = (float)(tg + 1);
        float rm = runx / n;
        float rv = runxx / n - rm * rm;
        xs[k][tid] = xv; rms[k][tid] = rm;
        rss[k][tid] = sqrtf(fmaxf(rv, 1e-8f));
    }
    __syncthreads();
    int tl = tid & 15, p = tid >> 4;
    const float* W0 = Wt + p * 768;
    float u0 = 0.f, u1 = 0.f, u2 = 0.f;
#pragma unroll 4
    for (int j4 = 0; j4 < 64; j4++) {
        float4 xv = *(float4*)&xs[tl][j4 * 4];
        float4 wx = *(const float4*)(W0 + j4 * 4);
        float4 rv = *(float4*)&rms[tl][j4 * 4];
        float4 wr = *(const float4*)(W0 + 256 + j4 * 4);
        float4 sv = *(float4*)&rss[tl][j4 * 4];
        float4 wz = *(const float4*)(W0 + 512 + j4 * 4);
        u0 += xv.x * wx.x + xv.y * wx.y + xv.z * wx.z + xv.w * wx.w;
        u1 += rv.x * wr.x + rv.y * wr.y + rv.z * wr.z + rv.w * wr.w;
        u2 += sv.x * wz.x + sv.y * wz.y + sv.z * wz.z + sv.w * wz.w;
    }
    float z = tanhf(u0 + u1 + u2) * PI_F;
    float si, co; sincosf(z, &si, &co);
    int tg = s * 16 + tl;
    czsz[((size_t)(b * L + tg)) * 32 + p] = co;
    czsz[((size_t)(b * L + tg)) * 32 + 16 + p] = si;
}

// ------------- half-chunk outer-product sums Sh[b,c,h,f,d] (32-t halves) --------
__global__ __launch_bounds__(256) void outer_sums_kernel(
    const float* __restrict__ V, const float* __restrict__ fk,
    const float* __restrict__ posci, float* __restrict__ Sh) {
    int g = blockIdx.x >> 1, h = blockIdx.x & 1;
    int c = blockIdx.y;
    int b = blockIdx.z;
    int tid = threadIdx.x;
    __shared__ float Fk[32][40];
    int F0 = g * 36;
#pragma unroll
    for (int e = 0; e < 2; e++) {
        int idx = e * 256 + tid;     // 288 f4 = 32 rows x 9
        if (idx < 288) {
            int r = idx / 9, c4 = idx - r * 9;
            int tg = c * T + h * 32 + r;
            float4 v;
            if (g == 0) v = *(const float4*)(fk + ((size_t)(b * L + tg)) * 40 + c4 * 4);
            else if (c4 == 0) v = *(const float4*)(fk + ((size_t)(b * L + tg)) * 40 + 36);
            else v = *(const float4*)(posci + tg * 32 + (c4 - 1) * 4);
            *(float4*)&Fk[r][c4 * 4] = v;
        }
    }
    __syncthreads();
    float acc[36];
#pragma unroll
    for (int f = 0; f < 36; f++) acc[f] = 0.f;
    for (int t = 0; t < 32; t++) {
        float v = V[((size_t)(b * L + c * T + h * 32 + t)) * D + tid];
#pragma unroll
        for (int f4 = 0; f4 < 9; f4++) {
            float4 fkv = *(float4*)&Fk[t][f4 * 4];
            acc[f4 * 4 + 0] += fkv.x * v;
            acc[f4 * 4 + 1] += fkv.y * v;
            acc[f4 * 4 + 2] += fkv.z * v;
            acc[f4 * 4 + 3] += fkv.w * v;
        }
    }
    for (int f = 0; f < 36; f++)
        Sh[((((size_t)(b * C + c)) * 2 + h) * F + F0 + f) * D + tid] = acc[f];
}

// ------- exclusive prefix over chunks, combining half-chunk sums ---------------
__global__ __launch_bounds__(256) void prefix_kernel(const float* __restrict__ Sh,
                                                     float* __restrict__ S) {
    int bf = blockIdx.x;
    int b = bf / F, f = bf % F;
    int d = threadIdx.x;
    float v0[C], v1[C];
#pragma unroll
    for (int c = 0; c < C; c++) {
        v0[c] = Sh[((((size_t)(b * C + c)) * 2 + 0) * F + f) * D + d];
        v1[c] = Sh[((((size_t)(b * C + c)) * 2 + 1) * F + f) * D + d];
    }
    float run = 0.f;
#pragma unroll
    for (int c = 0; c < C; c++) {
        S[(((size_t)(b * C + c)) * F + f) * D + d] = run;
        run += v0[c] + v1[c];
    }
}

// ---------------- intra (fused score): ret = Fq·M + A·V -------------------------
// grid (8 = 4 tg x 2 dh, 32 c, B) = 1024 blocks; float4 staging via fk+posci.
__global__ __launch_bounds__(256) void intra_kernel(
    const float* __restrict__ V, float* __restrict__ ret,
    const float* __restrict__ fk, const float* __restrict__ fq,
    const float* __restrict__ posci, const float* __restrict__ Mexc,
    const float* __restrict__ pos_weight) {
    int tg = blockIdx.x >> 1, dh = blockIdx.x & 1;
    int c = blockIdx.y, b = blockIdx.z;
    int tid = threadIdx.x;
    int t0 = tg * 16;
    __shared__ float Fk[64][76];
    __shared__ float Fq[16][76];
    __shared__ float As[16][68];
    float posq = 0.5f / (1.0f + expf(-pos_weight[0]));
    // stage Fk: 64 rows x 18 f4 (10 from fk, 8 from posci)
#pragma unroll
    for (int e = 0; e < 5; e++) {
        int idx = e * 256 + tid;
        if (idx < 1152) {
            int r = idx / 18, c4 = idx - r * 18;
            int tgl = c * T + r;
            float4 v;
            if (c4 < 10) v = *(const float4*)(fk + ((size_t)(b * L + tgl)) * 40 + c4 * 4);
            else v = *(const float4*)(posci + tgl * 32 + (c4 - 10) * 4);
            *(float4*)&Fk[r][c4 * 4] = v;
        }
    }
    // stage Fq: 16 rows x 18 f4; pos part scaled by posq
#pragma unroll
    for (int e = 0; e < 2; e++) {
        int idx = e * 256 + tid;
        if (idx < 288) {
            int r = idx / 18, c4 = idx - r * 18;
            int tgl = c * T + t0 + r;
            float4 v;
            if (c4 < 10) v = *(const float4*)(fq + ((size_t)(b * L + tgl)) * 40 + c4 * 4);
            else {
                v = *(const float4*)(posci + tgl * 32 + (c4 - 10) * 4);
                v.x *= posq; v.y *= posq; v.z *= posq; v.w *= posq;
            }
            *(float4*)&Fq[r][c4 * 4] = v;
        }
    }
    __syncthreads();
    // A[r][k]: 16 x 64, 4 k's per thread; hoisted Fq fragment, mask after
    {
        int r = tid >> 4, k0 = (tid & 15) * 4;
        int tglob = t0 + r;
        float a0 = 0.f, a1 = 0.f, a2 = 0.f, a3 = 0.f;
#pragma unroll
        for (int f4 = 0; f4 < 18; f4++) {
            float4 q = *(float4*)&Fq[r][f4 * 4];
            float4 k0v = *(float4*)&Fk[k0 + 0][f4 * 4];
            float4 k1v = *(float4*)&Fk[k0 + 1][f4 * 4];
            float4 k2v = *(float4*)&Fk[k0 + 2][f4 * 4];
            float4 k3v = *(float4*)&Fk[k0 + 3][f4 * 4];
            a0 += q.x * k0v.x + q.y * k0v.y + q.z * k0v.z + q.w * k0v.w;
            a1 += q.x * k1v.x + q.y * k1v.y + q.z * k1v.z + q.w * k1v.w;
            a2 += q.x * k2v.x + q.y * k2v.y + q.z * k2v.z + q.w * k2v.w;
            a3 += q.x * k3v.x + q.y * k3v.y + q.z * k3v.z + q.w * k3v.w;
        }
        float4 av = make_float4((k0 + 0 <= tglob) ? a0 : 0.f, (k0 + 1 <= tglob) ? a1 : 0.f,
                                (k0 + 2 <= tglob) ? a2 : 0.f, (k0 + 3 <= tglob) ? a3 : 0.f);
        *(float4*)&As[tid >> 4][k0] = av;
    }
    __syncthreads();
    // main: thread owns column d, 8 rows; stream M then V from global
    int dl = tid & 127, rowg = tid >> 7;
    int d = dh * 128 + dl;
    int r0 = rowg * 8;
    float acc[8];
#pragma unroll
    for (int i = 0; i < 8; i++) acc[i] = 0.f;
    const float* Mp = Mexc + (((size_t)(b * C + c)) * F) * D + d;
#pragma unroll 8
    for (int f = 0; f < F; f++) {
        float m = Mp[(size_t)f * D];
#pragma unroll
        for (int i = 0; i < 8; i++) acc[i] += Fq[r0 + i][f] * m;
    }
    const float* Vp = V + ((size_t)(b * L + c * T)) * D + d;
    int kmax = t0 + 16;
#pragma unroll 8
    for (int k = 0; k < kmax; k++) {
        float v = Vp[(size_t)k * D];
#pragma unroll
        for (int i = 0; i < 8; i++) acc[i] += As[r0 + i][k] * v;
    }
    float* Rp = ret + ((size_t)(b * L + c * T + t0 + r0)) * D + d;
#pragma unroll
    for (int i = 0; i < 8; i++) Rp[(size_t)i * D] = acc[i];
}

// ---------------- hprep: hn = LN((ret + lcoef*pers)/nrm)*gamma + beta -----------
__global__ __launch_bounds__(256) void hprep_kernel(
    const float* __restrict__ retp, const float* __restrict__ czsz,
    const float* __restrict__ ltm_mem, const float* __restrict__ ltm_count,
    const float* __restrict__ ltm_weight, const float* __restrict__ ln_gamma,
    const float* __restrict__ ln_beta, float* __restrict__ hn) {
    int rc = blockIdx.x;
    int b  = blockIdx.y;
    int row0 = rc * 16;
    int tid = threadIdx.x;
    __shared__ float hb[16][260];    // 260%32==4 -> stats stride-16 is 2-way (free)
    __shared__ float cs[16][33];
    __shared__ float part1[16][17], part2[16][17];
    __shared__ float mu[16], rsig[16];
    float lsig = 1.f / (1.f + expf(-ltm_weight[0]));
    float pnorm = sqrtf(fmaxf(ltm_count[0], 1.f) * (float)LTMP);
    float lcoef = lsig / pnorm;
    float Mre[16], Mim[16];
#pragma unroll
    for (int p = 0; p < 16; p++) {
        Mre[p] = ltm_mem[(p * D + tid) * 2];
        Mim[p] = ltm_mem[(p * D + tid) * 2 + 1];
    }
    float gam = ln_gamma[tid], bet = ln_beta[tid];
#pragma unroll
    for (int e = 0; e < 2; e++) {
        int idx = e * 256 + tid;     // 512 = 16 rows x 32
        int t = idx >> 5, q = idx & 31;
        cs[t][q] = czsz[((size_t)(b * L + row0 + t)) * 32 + q];
    }
    __syncthreads();
#pragma unroll 4
    for (int t = 0; t < 16; t++) {
        int tg = row0 + t;
        float pers = 0.f;
#pragma unroll
        for (int p = 0; p < 16; p++) pers += Mre[p] * cs[t][p] + Mim[p] * cs[t][16 + p];
        float rv = retp[((size_t)(b * L + tg)) * D + tid];
        hb[t][tid] = (rv + lcoef * pers) / (2.0f * sqrtf((float)(tg + 1)));
    }
    __syncthreads();
    {
        int row = tid & 15, e = tid >> 4;
        float s1 = 0.f, s2 = 0.f;
#pragma unroll
        for (int k = 0; k < 16; k++) {
            float v = hb[row][e + 16 * k];
            s1 += v; s2 += v * v;
        }
        part1[row][e] = s1; part2[row][e] = s2;
    }
    __syncthreads();
    if (tid < 16) {
        float s1 = 0.f, s2 = 0.f;
#pragma unroll
        for (int e = 0; e < 16; e++) { s1 += part1[tid][e]; s2 += part2[tid][e]; }
        float m = s1 / 256.f;
        mu[tid] = m;
        rsig[tid] = rsqrtf(fmaxf(s2 / 256.f - m * m, 0.f) + 1e-5f);
    }
    __syncthreads();
#pragma unroll 4
    for (int t = 0; t < 16; t++)
        hn[((size_t)(b * L + row0 + t)) * D + tid] =
            (hb[t][tid] - mu[t]) * rsig[t] * gam + bet;
}

// ---------------- gemm_out: out = x + hn @ w_out + b_out ------------------------
__global__ __launch_bounds__(256) void gemm_out_kernel(
    const float* __restrict__ hn, const float* __restrict__ w_out,
    const float* __restrict__ b_out, const float* __restrict__ x,
    float* __restrict__ out) {
    int cg = blockIdx.x;
    int rc = blockIdx.y;
    int b  = blockIdx.z;
    int row0 = rc * 64;
    int tid = threadIdx.x;
    __shared__ float hs[2][32][74];
    __shared__ float wo[2][32][68];
    int rg = tid >> 4, cgi = tid & 15;
    int r0 = rg * 4, c0 = cgi * 4;
    float acc[4][4];
#pragma unroll
    for (int i = 0; i < 4; i++)
#pragma unroll
        for (int e = 0; e < 4; e++) acc[i][e] = 0.f;
    int rrA = tid >> 3, k4A = tid & 7;
    int jA = tid >> 4, c4A = tid & 15;
    float4 hr0, hr1, wr0, wr1;

#define ISSUE_LOADS(kb_)                                                            \
    {                                                                               \
        hr0 = *(const float4*)(hn + ((size_t)(b * L + row0 + rrA)) * D + (kb_) + k4A * 4);      \
        hr1 = *(const float4*)(hn + ((size_t)(b * L + row0 + 32 + rrA)) * D + (kb_) + k4A * 4); \
        wr0 = *(const float4*)(w_out + (size_t)((kb_) + jA) * D + cg * 64 + c4A * 4);           \
        wr1 = *(const float4*)(w_out + (size_t)((kb_) + 16 + jA) * D + cg * 64 + c4A * 4);      \
    }
#define WRITE_LDS(bi)                                                               \
    {                                                                               \
        const float* hp0 = (const float*)&hr0;                                      \
        const float* hp1 = (const float*)&hr1;                                      \
        _Pragma("unroll")                                                           \
        for (int u = 0; u < 4; u++) {                                               \
            hs[bi][k4A * 4 + u][rrA] = hp0[u];                                      \
            hs[bi][k4A * 4 + u][32 + rrA] = hp1[u];                                 \
        }                                                                           \
        *(float4*)&wo[bi][jA][c4A * 4] = wr0;                                       \
        *(float4*)&wo[bi][16 + jA][c4A * 4] = wr1;                                  \
    }

    ISSUE_LOADS(0);
    WRITE_LDS(0);
    __syncthreads();
    for (int kc = 0; kc < 8; kc++) {
        if (kc < 7) ISSUE_LOADS((kc + 1) * 32);
        int bi = kc & 1;
#pragma unroll 8
        for (int j = 0; j < 32; j++) {
            float2 xlo = *(float2*)&hs[bi][j][r0];
            float2 xhi = *(float2*)&hs[bi][j][r0 + 2];
            float4 wv = *(float4*)&wo[bi][j][c0];
            acc[0][0] += xlo.x * wv.x; acc[0][1] += xlo.x * wv.y; acc[0][2] += xlo.x * wv.z; acc[0][3] += xlo.x * wv.w;
            acc[1][0] += xlo.y * wv.x; acc[1][1] += xlo.y * wv.y; acc[1][2] += xlo.y * wv.z; acc[1][3] += xlo.y * wv.w;
            acc[2][0] += xhi.x * wv.x; acc[2][1] += xhi.x * wv.y; acc[2][2] += xhi.x * wv.z; acc[2][3] += xhi.x * wv.w;
            acc[3][0] += xhi.y * wv.x; acc[3][1] += xhi.y * wv.y; acc[3][2] += xhi.y * wv.z; acc[3][3] += xhi.y * wv.w;
        }
        if (kc < 7) WRITE_LDS((kc + 1) & 1);
        __syncthreads();
    }
#undef ISSUE_LOADS
#undef WRITE_LDS
    {
        int d0 = cg * 64 + c0;
        float4 bo = *(const float4*)(b_out + d0);
#pragma unroll
        for (int i = 0; i < 4; i++) {
            size_t o = ((size_t)(b * L + row0 + r0 + i)) * D + d0;
            float4 xa = *(const float4*)(x + o);
            *(float4*)(out + o) = make_float4(xa.x + acc[i][0] + bo.x, xa.y + acc[i][1] + bo.y,
                                              xa.z + acc[i][2] + bo.z, xa.w + acc[i][3] + bo.w);
        }
    }
}

extern "C" void kernel_launch(void* const* d_in, const int* in_sizes, int n_in,
                              void* d_out, int out_size, void* d_ws, size_t ws_size,
                              hipStream_t stream) {
    (void)in_sizes; (void)n_in; (void)out_size; (void)ws_size;
    const float* x            = (const float*)d_in[0];
    const float* key_proj     = (const float*)d_in[1];
    const float* query_proj   = (const float*)d_in[2];
    const float* ltm_key_proj = (const float*)d_in[3];
    const float* pos_freqs    = (const float*)d_in[4];
    const float* w_value      = (const float*)d_in[5];
    const float* b_value      = (const float*)d_in[6];
    const float* ln_gamma     = (const float*)d_in[9];
    const float* ln_beta      = (const float*)d_in[10];
    const float* w_out        = (const float*)d_in[11];
    const float* b_out        = (const float*)d_in[12];
    const float* set_weights  = (const float*)d_in[13];
    const float* pos_weight   = (const float*)d_in[14];
    const float* surprise_scale      = (const float*)d_in[15];
    const float* surprise_bias       = (const float*)d_in[16];
    const float* resonance_scale     = (const float*)d_in[17];
    const float* resonance_threshold = (const float*)d_in[18];
    const float* ltm_weight   = (const float*)d_in[19];
    const float* ltm_mem      = (const float*)d_in[20];
    const float* ltm_count    = (const float*)d_in[21];
    float* out = (float*)d_out;

    float* ws = (float*)d_ws;
    size_t off = 0;
    float* V     = ws + off; off += (size_t)B * L * D;   // reused as hn after intra
    float* ret   = ws + off; off += (size_t)B * L * D;
    float* fk    = ws + off; off += (size_t)B * L * 40;
    float* fq    = ws + off; off += (size_t)B * L * 40;
    float* posci = ws + off; off += (size_t)L * 32;
    float* Sx16  = ws + off; off += (size_t)B * 128 * D;
    float* Sxx16 = ws + off; off += (size_t)B * 128 * D;
    float* czsz  = ws + off; off += (size_t)B * L * 32;
    float* Sh    = ws + off; off += (size_t)B * C * 2 * F * D;   // half-chunk sums
    float* S     = ws + off; off += (size_t)B * C * F * D;       // exclusive prefix
    float* Wt    = ws + off; off += (size_t)16 * 768;
    float* partial  = ws + off; off += (size_t)B * 64 * 8;
    float* chunkoff = ws + off; off += (size_t)B * 64 * 8;
    float* hn = V;   // V retired after intra reads it

    prep_kernel<<<dim3(688), 256, 0, stream>>>(pos_freqs, ltm_key_proj, x, posci, Wt,
                                               Sx16, Sxx16);
    featurize_kernel<<<dim3(4, 32, B), 256, 0, stream>>>(x, key_proj, query_proj, w_value,
                                                         b_value, set_weights, V, fk, fq, partial);
    gs_scan_kernel<<<dim3(B), 512, 0, stream>>>(partial, chunkoff);
    gs_apply_kernel<<<dim3(64, B), 256, 0, stream>>>(fk, chunkoff, surprise_scale, surprise_bias,
                                                     resonance_scale, resonance_threshold);
    ltm_z_kernel<<<dim3(128, B), 256, 0, stream>>>(x, Sx16, Sxx16, Wt, czsz);
    outer_sums_kernel<<<dim3(4, C, B), 256, 0, stream>>>(V, fk, posci, Sh);
    prefix_kernel<<<dim3(B * F), 256, 0, stream>>>(Sh, S);
    intra_kernel<<<dim3(8, C, B), 256, 0, stream>>>(V, ret, fk, fq, posci, S, pos_weight);
    hprep_kernel<<<dim3(128, B), 256, 0, stream>>>(ret, czsz, ltm_mem, ltm_count, ltm_weight,
                                                   ln_gamma, ln_beta, hn);
    gemm_out_kernel<<<dim3(4, 32, B), 256, 0, stream>>>(hn, w_out, b_out, x, out);
}

// Round 13
// 221.526 us; speedup vs baseline: 1.2731x; 1.1113x over previous
//
#include <hip/hip_runtime.h>
#include <math.h>

#define B 4
#define L 2048
#define D 256
#define POSP 16
#define LTMP 16
#define T 64
#define C 32
#define F 72
#define PI_F 3.14159274101257324f
#define TWO_PI_D 6.283185307179586476925286766559

// -- prep: pos phasors (interleaved) + Wt transpose + 16-row x/x^2 sums ----------
// grid 688: [0,128) pos, [128,176) Wt, [176,688) stats16 (512 = 128 s-chunks x B)
__global__ __launch_bounds__(256) void prep_kernel(const float* __restrict__ pos_freqs,
                                                   const float* __restrict__ lkp,
                                                   const float* __restrict__ x,
                                                   float* __restrict__ posci,
                                                   float* __restrict__ Wt,
                                                   float* __restrict__ Sx16,
                                                   float* __restrict__ Sxx16) {
    int bid = blockIdx.x;
    int tid = threadIdx.x;
    if (bid < 128) {
        int idx = bid * 256 + tid;
        int t = idx >> 4, p = idx & 15;
        float a = (float)t * pos_freqs[p];   // replicate numpy op order in fp32
        float th = (a * 2.0f) * PI_F;
        double r = fmod((double)th, TWO_PI_D);
        posci[t * 32 + 2 * p] = (float)cos(r);
        posci[t * 32 + 2 * p + 1] = (float)sin(r);
    } else if (bid < 176) {
        int i2 = (bid - 128) * 256 + tid;
        if (i2 < 16 * 768) {
            int p = i2 / 768, j = i2 - p * 768;
            Wt[i2] = lkp[j * 16 + p];
        }
    } else {
        int sb = bid - 176;          // 0..511
        int s = sb & 127, b = sb >> 7;
        float sx = 0.f, sxx = 0.f;
#pragma unroll
        for (int k = 0; k < 16; k++) {
            float v = x[((size_t)(b * L + s * 16 + k)) * D + tid];
            sx += v; sxx += v * v;
        }
        Sx16[((size_t)(b * 128 + s)) * D + tid] = sx;
        Sxx16[((size_t)(b * 128 + s)) * D + tid] = sxx;
    }
}

// ---------------- featurize: fused GEMM x @ [w_value | key_proj | query_proj] ---
__global__ __launch_bounds__(256) void featurize_kernel(
    const float* __restrict__ x, const float* __restrict__ key_proj,
    const float* __restrict__ query_proj, const float* __restrict__ w_value,
    const float* __restrict__ b_value, const float* __restrict__ set_weights,
    float* __restrict__ V, float* __restrict__ fk, float* __restrict__ fq,
    float* __restrict__ partial) {
    int cg = blockIdx.x;
    int rc = blockIdx.y;
    int b  = blockIdx.z;
    int row0 = rc * 64;
    int tid = threadIdx.x;
    __shared__ float xs[2][32][74];   // [buf][k][row] transposed x, stride 74
    __shared__ float ws[2][32][84];   // [buf][k][64 V-cols + 16 proj cols]
    __shared__ float zbuf[64][20];
    __shared__ float jkv[64][9];
    const bool has_proj = (cg < 2);
    const float* proj = (cg == 0) ? key_proj : query_proj;
    int rg = tid >> 4, cgi = tid & 15;
    int r0 = rg * 4, c0 = cgi * 4;
    int prow = tid >> 2, pc4 = tid & 3;
    float acc[4][4], accp[4];
#pragma unroll
    for (int i = 0; i < 4; i++) {
#pragma unroll
        for (int e = 0; e < 4; e++) acc[i][e] = 0.f;
        accp[i] = 0.f;
    }
    int rrA = tid >> 3, k4A = tid & 7;     // x stage mapping
    int jA = tid >> 4, c4A = tid & 15;     // w stage mapping
    float4 xr0, xr1, wr0, wr1, prr;

#define ISSUE_LOADS(kb_)                                                            \
    {                                                                               \
        xr0 = *(const float4*)(x + ((size_t)(b * L + row0 + rrA)) * D + (kb_) + k4A * 4);      \
        xr1 = *(const float4*)(x + ((size_t)(b * L + row0 + 32 + rrA)) * D + (kb_) + k4A * 4); \
        wr0 = *(const float4*)(w_value + (size_t)((kb_) + jA) * D + cg * 64 + c4A * 4);        \
        wr1 = *(const float4*)(w_value + (size_t)((kb_) + 16 + jA) * D + cg * 64 + c4A * 4);   \
        if (has_proj && tid < 128)                                                  \
            prr = *(const float4*)(proj + (size_t)((kb_) + (tid >> 2)) * 16 + (tid & 3) * 4);  \
    }
#define WRITE_LDS(bi)                                                               \
    {                                                                               \
        const float* xp0 = (const float*)&xr0;                                      \
        const float* xp1 = (const float*)&xr1;                                      \
        _Pragma("unroll")                                                           \
        for (int u = 0; u < 4; u++) {                                               \
            xs[bi][k4A * 4 + u][rrA] = xp0[u];                                      \
            xs[bi][k4A * 4 + u][32 + rrA] = xp1[u];                                 \
        }                                                                           \
        *(float4*)&ws[bi][jA][c4A * 4] = wr0;                                       \
        *(float4*)&ws[bi][16 + jA][c4A * 4] = wr1;                                  \
        if (has_proj && tid < 128)                                                  \
            *(float4*)&ws[bi][tid >> 2][64 + (tid & 3) * 4] = prr;                  \
    }

    ISSUE_LOADS(0);
    WRITE_LDS(0);
    __syncthreads();
    for (int kc = 0; kc < 8; kc++) {
        if (kc < 7) ISSUE_LOADS((kc + 1) * 32);
        int bi = kc & 1;
#pragma unroll 8
        for (int j = 0; j < 32; j++) {
            float2 xlo = *(float2*)&xs[bi][j][r0];
            float2 xhi = *(float2*)&xs[bi][j][r0 + 2];
            float4 wv = *(float4*)&ws[bi][j][c0];
            acc[0][0] += xlo.x * wv.x; acc[0][1] += xlo.x * wv.y; acc[0][2] += xlo.x * wv.z; acc[0][3] += xlo.x * wv.w;
            acc[1][0] += xlo.y * wv.x; acc[1][1] += xlo.y * wv.y; acc[1][2] += xlo.y * wv.z; acc[1][3] += xlo.y * wv.w;
            acc[2][0] += xhi.x * wv.x; acc[2][1] += xhi.x * wv.y; acc[2][2] += xhi.x * wv.z; acc[2][3] += xhi.x * wv.w;
            acc[3][0] += xhi.y * wv.x; acc[3][1] += xhi.y * wv.y; acc[3][2] += xhi.y * wv.z; acc[3][3] += xhi.y * wv.w;
            if (has_proj) {
                float xp = xs[bi][j][prow];
                float4 wp = *(float4*)&ws[bi][j][64 + pc4 * 4];
                accp[0] += xp * wp.x; accp[1] += xp * wp.y;
                accp[2] += xp * wp.z; accp[3] += xp * wp.w;
            }
        }
        if (kc < 7) WRITE_LDS((kc + 1) & 1);
        __syncthreads();
    }
#undef ISSUE_LOADS
#undef WRITE_LDS

    // V epilogue
    {
        int d0 = cg * 64 + c0;
        float4 bv = *(const float4*)(b_value + d0);
#pragma unroll
        for (int i = 0; i < 4; i++) {
            size_t o = ((size_t)(b * L + row0 + r0 + i)) * D + d0;
            *(float4*)(V + o) = make_float4(acc[i][0] + bv.x, acc[i][1] + bv.y,
                                            acc[i][2] + bv.z, acc[i][3] + bv.w);
        }
    }
    if (!has_proj) return;
#pragma unroll
    for (int e = 0; e < 4; e++) zbuf[prow][pc4 * 4 + e] = tanhf(accp[e]) * PI_F;
    __syncthreads();
    // phasor epilogue: 64 rows x 4 threads; thread handles 4 cols + joint plane q
    {
        int tt = tid >> 2, q = tid & 3;
        size_t bt = (size_t)(b * L + row0 + tt);
        if (cg == 0) {
            float* fp = fk + bt * 40;
#pragma unroll
            for (int e = 0; e < 4; e++) {
                int col = q * 4 + e;
                float si, co; sincosf(zbuf[tt][col], &si, &co);
                fp[2 * col] = co; fp[2 * col + 1] = si;
            }
            float zs = zbuf[tt][q] + zbuf[tt][4 + q] + zbuf[tt][8 + q] + zbuf[tt][12 + q];
            float si, co; sincosf(zs, &si, &co);
            fp[32 + 2 * q] = co; fp[33 + 2 * q] = si;
            jkv[tt][2 * q] = co; jkv[tt][2 * q + 1] = si;
        } else {
            float sw0 = set_weights[0], sw1 = set_weights[1], sw2 = set_weights[2], sw3 = set_weights[3];
            float mx = fmaxf(fmaxf(sw0, sw1), fmaxf(sw2, sw3));
            float e0 = expf(sw0 - mx), e1 = expf(sw1 - mx), e2 = expf(sw2 - mx), e3 = expf(sw3 - mx);
            float esum = e0 + e1 + e2 + e3;
            float wsoft[4] = {e0 / esum, e1 / esum, e2 / esum, e3 / esum};
            float* fp = fq + bt * 40;
#pragma unroll
            for (int e = 0; e < 4; e++) {
                int col = q * 4 + e;
                float si, co; sincosf(zbuf[tt][col], &si, &co);
                float sc = 0.1f * wsoft[col >> 2];   // 0.5 * w_s / (NSETS+1)
                fp[2 * col] = sc * co; fp[2 * col + 1] = sc * si;
            }
            float zs = zbuf[tt][q] + zbuf[tt][4 + q] + zbuf[tt][8 + q] + zbuf[tt][12 + q];
            float si, co; sincosf(zs, &si, &co);
            fp[32 + 2 * q] = 0.1f * co; fp[33 + 2 * q] = 0.1f * si;
        }
    }
    __syncthreads();
    if (cg == 0) {   // reduce ungated jk over two 32-row halves -> 2 chunk partials
        int h = tid >> 7, idxr = tid & 127;
        int rr2 = idxr >> 3, ch = idxr & 7;
#pragma unroll
        for (int s2 = 16; s2 >= 1; s2 >>= 1) {
            if (rr2 < s2) jkv[h * 32 + rr2][ch] += jkv[h * 32 + rr2 + s2][ch];
            __syncthreads();
        }
        if (rr2 == 0) partial[((size_t)(b * 64 + rc * 2 + h)) * 8 + ch] = jkv[h * 32][ch];
    }
}

// ---------------- gate scan phase 2: exclusive scan of 64 chunk partials --------
__global__ __launch_bounds__(512) void gs_scan_kernel(const float* __restrict__ partial,
                                                      float* __restrict__ chunkoff) {
    int b = blockIdx.x;
    int tid = threadIdx.x;   // 512 = 64 chunks x 8 ch
    int c = tid >> 3, ch = tid & 7;
    __shared__ float sc_[64][9];
    float own = partial[((size_t)(b * 64 + c)) * 8 + ch];
    sc_[c][ch] = own;
    __syncthreads();
    for (int off = 1; off < 64; off <<= 1) {
        float v = 0.f;
        if (c >= off) v = sc_[c - off][ch];
        __syncthreads();
        if (c >= off) sc_[c][ch] += v;
        __syncthreads();
    }
    chunkoff[((size_t)(b * 64 + c)) * 8 + ch] = sc_[c][ch] - own;
}

// ---------------- gate scan phase 3: local scan, gate, scale fk -----------------
__global__ __launch_bounds__(256) void gs_apply_kernel(
    float* __restrict__ fk, const float* __restrict__ chunkoff,
    const float* __restrict__ surprise_scale, const float* __restrict__ surprise_bias,
    const float* __restrict__ resonance_scale, const float* __restrict__ resonance_threshold) {
    int rc = blockIdx.x, b = blockIdx.y;
    int tid = threadIdx.x;
    int t = tid >> 3, ch = tid & 7;
    __shared__ float sc_[32][9];
    __shared__ float gbuf[32];
    float* fp = fk + ((size_t)(b * L + rc * 32 + t)) * 40;
    float own = fp[32 + ch];
    sc_[t][ch] = own;
    __syncthreads();
    for (int off = 1; off < 32; off <<= 1) {
        float v = 0.f;
        if (t >= off) v = sc_[t - off][ch];
        __syncthreads();
        if (t >= off) sc_[t][ch] += v;
        __syncthreads();
    }
    float run = chunkoff[((size_t)(b * 64 + rc)) * 8 + ch] + sc_[t][ch] - own;
    __syncthreads();
    sc_[t][ch] = run;
    __syncthreads();
    if (tid < 32) {
        int tg = rc * 32 + tid;
        float r0 = sc_[tid][0], r1 = sc_[tid][1], r2 = sc_[tid][2], r3 = sc_[tid][3];
        float r4 = sc_[tid][4], r5 = sc_[tid][5], r6 = sc_[tid][6], r7 = sc_[tid][7];
        float rmag = 0.25f * (sqrtf(r0 * r0 + r1 * r1) + sqrtf(r2 * r2 + r3 * r3) +
                              sqrtf(r4 * r4 + r5 * r5) + sqrtf(r6 * r6 + r7 * r7));
        float scv = fminf(fmaxf(resonance_scale[0], 1.f), 20.f);
        float thv = fminf(fmaxf(resonance_threshold[0], 0.1f), 0.9f);
        float nres = rmag / sqrtf(fmaxf((float)tg, 1.0f));
        float surprise = 0.5f * (1.0f - tanhf(scv * (nres - thv)));
        gbuf[tid] = 1.0f / (1.0f + expf(-(surprise_scale[0] * (surprise - 0.5f) + surprise_bias[0])));
    }
    __syncthreads();
    float gv = gbuf[t];
#pragma unroll
    for (int e = 0; e < 5; e++) fp[ch * 5 + e] *= gv;
}

// ---------------- LTM phasor angles, 16 rows per block --------------------------
__global__ __launch_bounds__(256) void ltm_z_kernel(
    const float* __restrict__ x, const float* __restrict__ Sx16,
    const float* __restrict__ Sxx16, const float* __restrict__ Wt,
    float* __restrict__ czsz) {
    int s = blockIdx.x, b = blockIdx.y;
    int tid = threadIdx.x;
    __shared__ float xs[16][260], rms[16][260], rss[16][260];
    float a0 = 0.f, a1 = 0.f, a2 = 0.f, a3 = 0.f;
    float c0 = 0.f, c1 = 0.f, c2 = 0.f, c3 = 0.f;
    int sp = 0;
    for (; sp + 4 <= s; sp += 4) {
        a0 += Sx16[((size_t)(b * 128 + sp)) * D + tid];
        a1 += Sx16[((size_t)(b * 128 + sp + 1)) * D + tid];
        a2 += Sx16[((size_t)(b * 128 + sp + 2)) * D + tid];
        a3 += Sx16[((size_t)(b * 128 + sp + 3)) * D + tid];
        c0 += Sxx16[((size_t)(b * 128 + sp)) * D + tid];
        c1 += Sxx16[((size_t)(b * 128 + sp + 1)) * D + tid];
        c2 += Sxx16[((size_t)(b * 128 + sp + 2)) * D + tid];
        c3 += Sxx16[((size_t)(b * 128 + sp + 3)) * D + tid];
    }
    for (; sp < s; sp++) {
        a0 += Sx16[((size_t)(b * 128 + sp)) * D + tid];
        c0 += Sxx16[((size_t)(b * 128 + sp)) * D + tid];
    }
    float runx = (a0 + a1) + (a2 + a3), runxx = (c0 + c1) + (c2 + c3);
    for (int k = 0; k < 16; k++) {
        int tg = s * 16 + k;
        float xv = x[((size_t)(b * L + tg)) * D + tid];
        runx += xv; runxx += xv * xv;
        float n = (float)(tg + 1);
        float rm = runx / n;
        float rv = runxx / n - rm * rm;
        xs[k][tid] = xv; rms[k][tid] = rm;
        rss[k][tid] = sqrtf(fmaxf(rv, 1e-8f));
    }
    __syncthreads();
    int tl = tid & 15, p = tid >> 4;
    const float* W0 = Wt + p * 768;
    float u0 = 0.f, u1 = 0.f, u2 = 0.f;
#pragma unroll 4
    for (int j4 = 0; j4 < 64; j4++) {
        float4 xv = *(float4*)&xs[tl][j4 * 4];
        float4 wx = *(const float4*)(W0 + j4 * 4);
        float4 rv = *(float4*)&rms[tl][j4 * 4];
        float4 wr = *(const float4*)(W0 + 256 + j4 * 4);
        float4 sv = *(float4*)&rss[tl][j4 * 4];
        float4 wz = *(const float4*)(W0 + 512 + j4 * 4);
        u0 += xv.x * wx.x + xv.y * wx.y + xv.z * wx.z + xv.w * wx.w;
        u1 += rv.x * wr.x + rv.y * wr.y + rv.z * wr.z + rv.w * wr.w;
        u2 += sv.x * wz.x + sv.y * wz.y + sv.z * wz.z + sv.w * wz.w;
    }
    float z = tanhf(u0 + u1 + u2) * PI_F;
    float si, co; sincosf(z, &si, &co);
    int tg = s * 16 + tl;
    czsz[((size_t)(b * L + tg)) * 32 + p] = co;
    czsz[((size_t)(b * L + tg)) * 32 + 16 + p] = si;
}

// ------------- half-chunk outer-product sums Sh[b,c,h,f,d] (32-t halves) --------
__global__ __launch_bounds__(256) void outer_sums_kernel(
    const float* __restrict__ V, const float* __restrict__ fk,
    const float* __restrict__ posci, float* __restrict__ Sh) {
    int g = blockIdx.x >> 1, h = blockIdx.x & 1;
    int c = blockIdx.y;
    int b = blockIdx.z;
    int tid = threadIdx.x;
    __shared__ float Fk[32][40];
    int F0 = g * 36;
#pragma unroll
    for (int e = 0; e < 2; e++) {
        int idx = e * 256 + tid;     // 288 f4 = 32 rows x 9
        if (idx < 288) {
            int r = idx / 9, c4 = idx - r * 9;
            int tg = c * T + h * 32 + r;
            float4 v;
            if (g == 0) v = *(const float4*)(fk + ((size_t)(b * L + tg)) * 40 + c4 * 4);
            else if (c4 == 0) v = *(const float4*)(fk + ((size_t)(b * L + tg)) * 40 + 36);
            else v = *(const float4*)(posci + tg * 32 + (c4 - 1) * 4);
            *(float4*)&Fk[r][c4 * 4] = v;
        }
    }
    __syncthreads();
    float acc[36];
#pragma unroll
    for (int f = 0; f < 36; f++) acc[f] = 0.f;
    for (int t = 0; t < 32; t++) {
        float v = V[((size_t)(b * L + c * T + h * 32 + t)) * D + tid];
#pragma unroll
        for (int f4 = 0; f4 < 9; f4++) {
            float4 fkv = *(float4*)&Fk[t][f4 * 4];
            acc[f4 * 4 + 0] += fkv.x * v;
            acc[f4 * 4 + 1] += fkv.y * v;
            acc[f4 * 4 + 2] += fkv.z * v;
            acc[f4 * 4 + 3] += fkv.w * v;
        }
    }
    for (int f = 0; f < 36; f++)
        Sh[((((size_t)(b * C + c)) * 2 + h) * F + F0 + f) * D + tid] = acc[f];
}

// ------- exclusive prefix over chunks, combining half-chunk sums ---------------
__global__ __launch_bounds__(256) void prefix_kernel(const float* __restrict__ Sh,
                                                     float* __restrict__ S) {
    int bf = blockIdx.x;
    int b = bf / F, f = bf % F;
    int d = threadIdx.x;
    float v0[C], v1[C];
#pragma unroll
    for (int c = 0; c < C; c++) {
        v0[c] = Sh[((((size_t)(b * C + c)) * 2 + 0) * F + f) * D + d];
        v1[c] = Sh[((((size_t)(b * C + c)) * 2 + 1) * F + f) * D + d];
    }
    float run = 0.f;
#pragma unroll
    for (int c = 0; c < C; c++) {
        S[(((size_t)(b * C + c)) * F + f) * D + d] = run;
        run += v0[c] + v1[c];
    }
}

// ---- intra fused w/ hprep, 512 threads: hn = LN((Fq·M + A·V + pers)/nrm)·g + b --
// grid (4 tg, 32 c, B) = 512 blocks x 8 waves (16 waves/CU, same as before).
// Fk staged + A computed ONCE per (tg,c); thread owns d = tid&255, 8 rows
// (half = tid>>8). hn written directly (separate buffer; V stays read-only).
__global__ __launch_bounds__(512) void intra_kernel(
    const float* __restrict__ V, float* __restrict__ hn,
    const float* __restrict__ fk, const float* __restrict__ fq,
    const float* __restrict__ posci, const float* __restrict__ Mexc,
    const float* __restrict__ pos_weight, const float* __restrict__ czsz,
    const float* __restrict__ ltm_mem, const float* __restrict__ ltm_count,
    const float* __restrict__ ltm_weight, const float* __restrict__ ln_gamma,
    const float* __restrict__ ln_beta) {
    int tg = blockIdx.x, c = blockIdx.y, b = blockIdx.z;
    int tid = threadIdx.x;
    int t0 = tg * 16;
    __shared__ float smem[8384];
    float (*Fk)[76] = (float(*)[76])smem;              // 64*76 = 4864
    float (*Fq)[76] = (float(*)[76])(smem + 4864);     // 16*76 -> 6080
    float (*As)[68] = (float(*)[68])(smem + 6080);     // 16*68 -> 7168
    float (*cs)[33]  = (float(*)[33])(smem + 7168);    // 528 -> 7696
    float (*part1)[17] = (float(*)[17])(smem + 7696);  // 272 -> 7968
    float (*part2)[17] = (float(*)[17])(smem + 7968);  // 272 -> 8240
    float* mu   = smem + 8240;
    float* rsig = smem + 8256;
    float (*hb)[260] = (float(*)[260])smem;            // aliases Fk (4160 <= 4864)
    float posq = 0.5f / (1.0f + expf(-pos_weight[0]));
    // stage Fk: 64 rows x 18 f4 (10 from fk, 8 from posci)
#pragma unroll
    for (int e = 0; e < 3; e++) {
        int idx = e * 512 + tid;
        if (idx < 1152) {
            int r = idx / 18, c4 = idx - r * 18;
            int tgl = c * T + r;
            float4 v;
            if (c4 < 10) v = *(const float4*)(fk + ((size_t)(b * L + tgl)) * 40 + c4 * 4);
            else v = *(const float4*)(posci + tgl * 32 + (c4 - 10) * 4);
            *(float4*)&Fk[r][c4 * 4] = v;
        }
    }
    // stage Fq: 16 rows x 18 f4; pos part scaled by posq
    if (tid < 288) {
        int r = tid / 18, c4 = tid - r * 18;
        int tgl = c * T + t0 + r;
        float4 v;
        if (c4 < 10) v = *(const float4*)(fq + ((size_t)(b * L + tgl)) * 40 + c4 * 4);
        else {
            v = *(const float4*)(posci + tgl * 32 + (c4 - 10) * 4);
            v.x *= posq; v.y *= posq; v.z *= posq; v.w *= posq;
        }
        *(float4*)&Fq[r][c4 * 4] = v;
    }
    // stage czsz: 512 = 16 rows x 32
    {
        int t = tid >> 5, q = tid & 31;
        cs[t][q] = czsz[((size_t)(b * L + c * T + t0 + t)) * 32 + q];
    }
    __syncthreads();
    // A[r][k]: 16 x 64; thread handles k = kA and kA+32 for row r (computed ONCE)
    {
        int r = tid >> 5, kA = tid & 31;
        int tglob = t0 + r;
        float a0 = 0.f, a1 = 0.f;
#pragma unroll
        for (int f4 = 0; f4 < 18; f4++) {
            float4 q = *(float4*)&Fq[r][f4 * 4];
            float4 kv0 = *(float4*)&Fk[kA][f4 * 4];
            float4 kv1 = *(float4*)&Fk[kA + 32][f4 * 4];
            a0 += q.x * kv0.x + q.y * kv0.y + q.z * kv0.z + q.w * kv0.w;
            a1 += q.x * kv1.x + q.y * kv1.y + q.z * kv1.z + q.w * kv1.w;
        }
        As[r][kA] = (kA <= tglob) ? a0 : 0.f;
        As[r][kA + 32] = (kA + 32 <= tglob) ? a1 : 0.f;
    }
    __syncthreads();   // Fk retired; region may be reused as hb
    // main: thread owns column d = tid&255, rows r0..r0+7 (r0 = (tid>>8)*8)
    int d = tid & 255, half = tid >> 8;
    int r0 = half * 8;
    float acc[8];
#pragma unroll
    for (int i = 0; i < 8; i++) acc[i] = 0.f;
    const float* Mp = Mexc + (((size_t)(b * C + c)) * F) * D + d;
#pragma unroll 8
    for (int f = 0; f < F; f++) {
        float m = Mp[(size_t)f * D];
#pragma unroll
        for (int i = 0; i < 8; i++) acc[i] += Fq[r0 + i][f] * m;
    }
    const float* Vp = V + ((size_t)(b * L + c * T)) * D + d;
    int kmax = t0 + r0 + 8;        // causality: rows r0..r0+7 need k <= t0+r0+7
#pragma unroll 8
    for (int k = 0; k < kmax; k++) {
        float v = Vp[(size_t)k * D];
#pragma unroll
        for (int i = 0; i < 8; i++) acc[i] += As[r0 + i][k] * v;
    }
    // + LTM pers, /nrm
    float lsig = 1.f / (1.f + expf(-ltm_weight[0]));
    float pnorm = sqrtf(fmaxf(ltm_count[0], 1.f) * (float)LTMP);
    float lcoef = lsig / pnorm;
    float Mre[16], Mim[16];
#pragma unroll
    for (int p = 0; p < 16; p++) {
        Mre[p] = ltm_mem[(p * D + d) * 2];
        Mim[p] = ltm_mem[(p * D + d) * 2 + 1];
    }
#pragma unroll
    for (int i = 0; i < 8; i++) {
        int row = r0 + i;
        float pers = 0.f;
#pragma unroll
        for (int p = 0; p < 16; p++) pers += Mre[p] * cs[row][p] + Mim[p] * cs[row][16 + p];
        int tgl = c * T + t0 + row;
        acc[i] = (acc[i] + lcoef * pers) / (2.0f * sqrtf((float)(tgl + 1)));
    }
    __syncthreads();   // all As/Fq/cs reads done before hb overwrite of Fk region
#pragma unroll
    for (int i = 0; i < 8; i++) hb[r0 + i][d] = acc[i];
    __syncthreads();
    // LN stats (tid<256): row = tid&15, e = tid>>4; cols e+16k -> 2-way banks
    if (tid < 256) {
        int row = tid & 15, e = tid >> 4;
        float s1 = 0.f, s2 = 0.f;
#pragma unroll
        for (int k = 0; k < 16; k++) {
            float v = hb[row][e + 16 * k];
            s1 += v; s2 += v * v;
        }
        part1[row][e] = s1; part2[row][e] = s2;
    }
    __syncthreads();
    if (tid < 16) {
        float s1 = 0.f, s2 = 0.f;
#pragma unroll
        for (int e = 0; e < 16; e++) { s1 += part1[tid][e]; s2 += part2[tid][e]; }
        float m = s1 / 256.f;
        mu[tid] = m;
        rsig[tid] = rsqrtf(fmaxf(s2 / 256.f - m * m, 0.f) + 1e-5f);
    }
    __syncthreads();
    float gam = ln_gamma[d], bet = ln_beta[d];
#pragma unroll
    for (int i = 0; i < 8; i++) {
        int row = r0 + i;
        hn[((size_t)(b * L + c * T + t0 + row)) * D + d] =
            (acc[i] - mu[row]) * rsig[row] * gam + bet;
    }
}

// ---------------- gemm_out: out = x + hn @ w_out + b_out ------------------------
__global__ __launch_bounds__(256) void gemm_out_kernel(
    const float* __restrict__ hn, const float* __restrict__ w_out,
    const float* __restrict__ b_out, const float* __restrict__ x,
    float* __restrict__ out) {
    int cg = blockIdx.x;
    int rc = blockIdx.y;
    int b  = blockIdx.z;
    int row0 = rc * 64;
    int tid = threadIdx.x;
    __shared__ float hs[2][32][74];
    __shared__ float wo[2][32][68];
    int rg = tid >> 4, cgi = tid & 15;
    int r0 = rg * 4, c0 = cgi * 4;
    float acc[4][4];
#pragma unroll
    for (int i = 0; i < 4; i++)
#pragma unroll
        for (int e = 0; e < 4; e++) acc[i][e] = 0.f;
    int rrA = tid >> 3, k4A = tid & 7;
    int jA = tid >> 4, c4A = tid & 15;
    float4 hr0, hr1, wr0, wr1;

#define ISSUE_LOADS(kb_)                                                            \
    {                                                                               \
        hr0 = *(const float4*)(hn + ((size_t)(b * L + row0 + rrA)) * D + (kb_) + k4A * 4);      \
        hr1 = *(const float4*)(hn + ((size_t)(b * L + row0 + 32 + rrA)) * D + (kb_) + k4A * 4); \
        wr0 = *(const float4*)(w_out + (size_t)((kb_) + jA) * D + cg * 64 + c4A * 4);           \
        wr1 = *(const float4*)(w_out + (size_t)((kb_) + 16 + jA) * D + cg * 64 + c4A * 4);      \
    }
#define WRITE_LDS(bi)                                                               \
    {                                                                               \
        const float* hp0 = (const float*)&hr0;                                      \
        const float* hp1 = (const float*)&hr1;                                      \
        _Pragma("unroll")                                                           \
        for (int u = 0; u < 4; u++) {                                               \
            hs[bi][k4A * 4 + u][rrA] = hp0[u];                                      \
            hs[bi][k4A * 4 + u][32 + rrA] = hp1[u];                                 \
        }                                                                           \
        *(float4*)&wo[bi][jA][c4A * 4] = wr0;                                       \
        *(float4*)&wo[bi][16 + jA][c4A * 4] = wr1;                                  \
    }

    ISSUE_LOADS(0);
    WRITE_LDS(0);
    __syncthreads();
    for (int kc = 0; kc < 8; kc++) {
        if (kc < 7) ISSUE_LOADS((kc + 1) * 32);
        int bi = kc & 1;
#pragma unroll 8
        for (int j = 0; j < 32; j++) {
            float2 xlo = *(float2*)&hs[bi][j][r0];
            float2 xhi = *(float2*)&hs[bi][j][r0 + 2];
            float4 wv = *(float4*)&wo[bi][j][c0];
            acc[0][0] += xlo.x * wv.x; acc[0][1] += xlo.x * wv.y; acc[0][2] += xlo.x * wv.z; acc[0][3] += xlo.x * wv.w;
            acc[1][0] += xlo.y * wv.x; acc[1][1] += xlo.y * wv.y; acc[1][2] += xlo.y * wv.z; acc[1][3] += xlo.y * wv.w;
            acc[2][0] += xhi.x * wv.x; acc[2][1] += xhi.x * wv.y; acc[2][2] += xhi.x * wv.z; acc[2][3] += xhi.x * wv.w;
            acc[3][0] += xhi.y * wv.x; acc[3][1] += xhi.y * wv.y; acc[3][2] += xhi.y * wv.z; acc[3][3] += xhi.y * wv.w;
        }
        if (kc < 7) WRITE_LDS((kc + 1) & 1);
        __syncthreads();
    }
#undef ISSUE_LOADS
#undef WRITE_LDS
    {
        int d0 = cg * 64 + c0;
        float4 bo = *(const float4*)(b_out + d0);
#pragma unroll
        for (int i = 0; i < 4; i++) {
            size_t o = ((size_t)(b * L + row0 + r0 + i)) * D + d0;
            float4 xa = *(const float4*)(x + o);
            *(float4*)(out + o) = make_float4(xa.x + acc[i][0] + bo.x, xa.y + acc[i][1] + bo.y,
                                              xa.z + acc[i][2] + bo.z, xa.w + acc[i][3] + bo.w);
        }
    }
}

extern "C" void kernel_launch(void* const* d_in, const int* in_sizes, int n_in,
                              void* d_out, int out_size, void* d_ws, size_t ws_size,
                              hipStream_t stream) {
    (void)in_sizes; (void)n_in; (void)out_size; (void)ws_size;
    const float* x            = (const float*)d_in[0];
    const float* key_proj     = (const float*)d_in[1];
    const float* query_proj   = (const float*)d_in[2];
    const float* ltm_key_proj = (const float*)d_in[3];
    const float* pos_freqs    = (const float*)d_in[4];
    const float* w_value      = (const float*)d_in[5];
    const float* b_value      = (const float*)d_in[6];
    const float* ln_gamma     = (const float*)d_in[9];
    const float* ln_beta      = (const float*)d_in[10];
    const float* w_out        = (const float*)d_in[11];
    const float* b_out        = (const float*)d_in[12];
    const float* set_weights  = (const float*)d_in[13];
    const float* pos_weight   = (const float*)d_in[14];
    const float* surprise_scale      = (const float*)d_in[15];
    const float* surprise_bias       = (const float*)d_in[16];
    const float* resonance_scale     = (const float*)d_in[17];
    const float* resonance_threshold = (const float*)d_in[18];
    const float* ltm_weight   = (const float*)d_in[19];
    const float* ltm_mem      = (const float*)d_in[20];
    const float* ltm_count    = (const float*)d_in[21];
    float* out = (float*)d_out;

    float* ws = (float*)d_ws;
    size_t off = 0;
    float* V     = ws + off; off += (size_t)B * L * D;
    float* hn    = ws + off; off += (size_t)B * L * D;   // intra writes hn directly
    float* fk    = ws + off; off += (size_t)B * L * 40;
    float* fq    = ws + off; off += (size_t)B * L * 40;
    float* posci = ws + off; off += (size_t)L * 32;
    float* Sx16  = ws + off; off += (size_t)B * 128 * D;
    float* Sxx16 = ws + off; off += (size_t)B * 128 * D;
    float* czsz  = ws + off; off += (size_t)B * L * 32;
    float* Sh    = ws + off; off += (size_t)B * C * 2 * F * D;   // half-chunk sums
    float* S     = ws + off; off += (size_t)B * C * F * D;       // exclusive prefix
    float* Wt    = ws + off; off += (size_t)16 * 768;
    float* partial  = ws + off; off += (size_t)B * 64 * 8;
    float* chunkoff = ws + off; off += (size_t)B * 64 * 8;

    prep_kernel<<<dim3(688), 256, 0, stream>>>(pos_freqs, ltm_key_proj, x, posci, Wt,
                                               Sx16, Sxx16);
    featurize_kernel<<<dim3(4, 32, B), 256, 0, stream>>>(x, key_proj, query_proj, w_value,
                                                         b_value, set_weights, V, fk, fq, partial);
    gs_scan_kernel<<<dim3(B), 512, 0, stream>>>(partial, chunkoff);
    gs_apply_kernel<<<dim3(64, B), 256, 0, stream>>>(fk, chunkoff, surprise_scale, surprise_bias,
                                                     resonance_scale, resonance_threshold);
    ltm_z_kernel<<<dim3(128, B), 256, 0, stream>>>(x, Sx16, Sxx16, Wt, czsz);
    outer_sums_kernel<<<dim3(4, C, B), 256, 0, stream>>>(V, fk, posci, Sh);
    prefix_kernel<<<dim3(B * F), 256, 0, stream>>>(Sh, S);
    intra_kernel<<<dim3(4, C, B), 512, 0, stream>>>(V, hn, fk, fq, posci, S, pos_weight,
                                                    czsz, ltm_mem, ltm_count, ltm_weight,
                                                    ln_gamma, ln_beta);
    gemm_out_kernel<<<dim3(4, 32, B), 256, 0, stream>>>(hn, w_out, b_out, x, out);
}